// Round 1
// baseline (3368.969 us; speedup 1.0000x reference)
//
#include <hip/hip_runtime.h>
#include <math.h>

#define E_DIM 1024
#define B_DIM 4
#define S_DIM 2048
#define H_DIM 16
#define D_HEAD 64
#define M_DIM (B_DIM * S_DIM)   // 8192

// ---------------- QKV projection GEMM ----------------
// C[M,N] = x[M,K] @ W[K,N] + b, scattered to [B,H,S,D]. z selects Q/K/V.
__global__ __launch_bounds__(256) void qkv_gemm(
    const float* __restrict__ A,
    const float* __restrict__ Wq, const float* __restrict__ bq,
    const float* __restrict__ Wk, const float* __restrict__ bk,
    const float* __restrict__ Wv, const float* __restrict__ bv,
    float* __restrict__ Qout, float* __restrict__ Kout, float* __restrict__ Vout)
{
    const int z = blockIdx.z;
    const float* W    = (z == 0) ? Wq : (z == 1) ? Wk : Wv;
    const float* bias = (z == 0) ? bq : (z == 1) ? bk : bv;
    float* Out        = (z == 0) ? Qout : (z == 1) ? Kout : Vout;

    const int m0 = blockIdx.x * 64;
    const int n0 = blockIdx.y * 64;
    const int tid = threadIdx.x;
    const int tx = tid & 15, ty = tid >> 4;

    __shared__ float As[16][68];   // [k][row], +4 pad: conflict-free, 16B-aligned rows
    __shared__ float Bs[16][64];   // [k][col]

    float c[4][4];
#pragma unroll
    for (int i = 0; i < 4; i++)
#pragma unroll
        for (int j = 0; j < 4; j++) c[i][j] = 0.f;

    for (int kc = 0; kc < E_DIM; kc += 16) {
#pragma unroll
        for (int r = 0; r < 4; r++) {
            int e = tid + r * 256;
            int row = e >> 4, col = e & 15;
            As[col][row] = A[(m0 + row) * E_DIM + kc + col];
        }
#pragma unroll
        for (int r = 0; r < 4; r++) {
            int e = tid + r * 256;
            int row = e >> 6, col = e & 63;
            Bs[row][col] = W[(kc + row) * E_DIM + n0 + col];
        }
        __syncthreads();
#pragma unroll
        for (int k = 0; k < 16; k++) {
            float4 av  = *(const float4*)&As[k][ty * 4];
            float4 bv4 = *(const float4*)&Bs[k][tx * 4];
            float a[4] = {av.x, av.y, av.z, av.w};
            float b[4] = {bv4.x, bv4.y, bv4.z, bv4.w};
#pragma unroll
            for (int i = 0; i < 4; i++)
#pragma unroll
                for (int j = 0; j < 4; j++) c[i][j] += a[i] * b[j];
        }
        __syncthreads();
    }

    // scatter: row m -> (b,s); col n -> (h,d); n0 is a multiple of 64 so h is fixed
    const int h = n0 >> 6;
#pragma unroll
    for (int i = 0; i < 4; i++) {
        int m = m0 + ty * 4 + i;
        int b = m >> 11;            // /S_DIM (2048)
        int s = m & (S_DIM - 1);
#pragma unroll
        for (int j = 0; j < 4; j++) {
            int d = tx * 4 + j;
            Out[(((size_t)(b * H_DIM + h) * S_DIM) + s) * D_HEAD + d] =
                c[i][j] + bias[n0 + d];
        }
    }
}

// ---------------- Output projection GEMM ----------------
__global__ __launch_bounds__(256) void out_gemm(
    const float* __restrict__ A, const float* __restrict__ W,
    const float* __restrict__ bias, float* __restrict__ Out)
{
    const int m0 = blockIdx.x * 64;
    const int n0 = blockIdx.y * 64;
    const int tid = threadIdx.x;
    const int tx = tid & 15, ty = tid >> 4;

    __shared__ float As[16][68];
    __shared__ float Bs[16][64];

    float c[4][4];
#pragma unroll
    for (int i = 0; i < 4; i++)
#pragma unroll
        for (int j = 0; j < 4; j++) c[i][j] = 0.f;

    for (int kc = 0; kc < E_DIM; kc += 16) {
#pragma unroll
        for (int r = 0; r < 4; r++) {
            int e = tid + r * 256;
            int row = e >> 4, col = e & 15;
            As[col][row] = A[(m0 + row) * E_DIM + kc + col];
        }
#pragma unroll
        for (int r = 0; r < 4; r++) {
            int e = tid + r * 256;
            int row = e >> 6, col = e & 63;
            Bs[row][col] = W[(kc + row) * E_DIM + n0 + col];
        }
        __syncthreads();
#pragma unroll
        for (int k = 0; k < 16; k++) {
            float4 av  = *(const float4*)&As[k][ty * 4];
            float4 bv4 = *(const float4*)&Bs[k][tx * 4];
            float a[4] = {av.x, av.y, av.z, av.w};
            float b[4] = {bv4.x, bv4.y, bv4.z, bv4.w};
#pragma unroll
            for (int i = 0; i < 4; i++)
#pragma unroll
                for (int j = 0; j < 4; j++) c[i][j] += a[i] * b[j];
        }
        __syncthreads();
    }

#pragma unroll
    for (int i = 0; i < 4; i++) {
        int m = m0 + ty * 4 + i;
#pragma unroll
        for (int j = 0; j < 4; j++) {
            int n = n0 + tx * 4 + j;
            Out[(size_t)m * E_DIM + n] = c[i][j] + bias[n];
        }
    }
}

// ---------------- Causal flash attention ----------------
// Q,K,V in [B,H,S,D]; O written in [B,S,E].
__global__ __launch_bounds__(256) void attn(
    const float* __restrict__ Q, const float* __restrict__ K,
    const float* __restrict__ V, float* __restrict__ O)
{
    const int bh = blockIdx.y;             // b*H + h
    const int q0 = blockIdx.x * 32;
    const int tid = threadIdx.x;
    const size_t base = (size_t)bh * S_DIM * D_HEAD;

    __shared__ float Qs[32][65], Ks[32][65], Vs[32][65];  // +1 pad: stride-64 conflicts killed
    __shared__ float Ss[32][33];
    __shared__ float row_m[32], row_l[32], row_scale[32];

    for (int e = tid; e < 32 * 64; e += 256) {
        int r = e >> 6, cdim = e & 63;
        Qs[r][cdim] = Q[base + (size_t)(q0 + r) * D_HEAD + cdim];
    }
    if (tid < 32) { row_m[tid] = -INFINITY; row_l[tid] = 0.f; }

    const int i  = tid >> 3;          // query row 0..31
    const int j0 = (tid * 4) & 31;    // key col base {0,4,...,28}
    const int d0 = (tid & 7) * 8;     // output d-chunk

    float acc[8];
#pragma unroll
    for (int r = 0; r < 8; r++) acc[r] = 0.f;

    for (int k0 = 0; k0 <= q0; k0 += 32) {
        __syncthreads();   // previous iter's readers of Ks/Vs/Ss done
        for (int e = tid; e < 32 * 64; e += 256) {
            int r = e >> 6, cdim = e & 63;
            Ks[r][cdim] = K[base + (size_t)(k0 + r) * D_HEAD + cdim];
            Vs[r][cdim] = V[base + (size_t)(k0 + r) * D_HEAD + cdim];
        }
        __syncthreads();

        // scores: each thread does row i, cols j0..j0+3
        float s0 = 0.f, s1 = 0.f, s2 = 0.f, s3 = 0.f;
#pragma unroll
        for (int d = 0; d < 64; d++) {
            float qv = Qs[i][d];
            s0 += qv * Ks[j0 + 0][d];
            s1 += qv * Ks[j0 + 1][d];
            s2 += qv * Ks[j0 + 2][d];
            s3 += qv * Ks[j0 + 3][d];
        }
        const float sc = 0.125f;  // 1/sqrt(64)
        const int qi = q0 + i;
        Ss[i][j0 + 0] = (k0 + j0 + 0 <= qi) ? s0 * sc : -INFINITY;
        Ss[i][j0 + 1] = (k0 + j0 + 1 <= qi) ? s1 * sc : -INFINITY;
        Ss[i][j0 + 2] = (k0 + j0 + 2 <= qi) ? s2 * sc : -INFINITY;
        Ss[i][j0 + 3] = (k0 + j0 + 3 <= qi) ? s3 * sc : -INFINITY;
        __syncthreads();

        // online softmax per row (32 threads)
        if (tid < 32) {
            float m_old = row_m[tid];
            float m_new = m_old;
#pragma unroll
            for (int j = 0; j < 32; j++) m_new = fmaxf(m_new, Ss[tid][j]);
            float l_add = 0.f;
#pragma unroll
            for (int j = 0; j < 32; j++) {
                float p = __expf(Ss[tid][j] - m_new);
                Ss[tid][j] = p;
                l_add += p;
            }
            float scale = __expf(m_old - m_new);   // 0 when m_old = -inf
            row_scale[tid] = scale;
            row_l[tid] = row_l[tid] * scale + l_add;
            row_m[tid] = m_new;
        }
        __syncthreads();

        // O accumulation: thread (i, d0..d0+7)
        float scale = row_scale[i];
#pragma unroll
        for (int r = 0; r < 8; r++) acc[r] *= scale;
        for (int j = 0; j < 32; j++) {
            float p = Ss[i][j];
#pragma unroll
            for (int r = 0; r < 8; r++) acc[r] += p * Vs[j][d0 + r];
        }
    }

    // write O in [B,S,E]: row b*S + (q0+i), col h*64 + d
    const int b = bh >> 4;            // /H_DIM
    const int h = bh & (H_DIM - 1);
    const float inv_l = 1.f / row_l[i];
    float* dst = O + ((size_t)(b * S_DIM + q0 + i) * E_DIM) + h * D_HEAD + d0;
#pragma unroll
    for (int r = 0; r < 8; r++) dst[r] = acc[r] * inv_l;
}

// ---------------- launch ----------------
extern "C" void kernel_launch(void* const* d_in, const int* in_sizes, int n_in,
                              void* d_out, int out_size, void* d_ws, size_t ws_size,
                              hipStream_t stream) {
    const float* x  = (const float*)d_in[0];
    const float* Wq = (const float*)d_in[1];
    const float* bq = (const float*)d_in[2];
    const float* Wk = (const float*)d_in[3];
    const float* bk = (const float*)d_in[4];
    const float* Wv = (const float*)d_in[5];
    const float* bv = (const float*)d_in[6];
    const float* Wo = (const float*)d_in[7];
    const float* bo = (const float*)d_in[8];

    float* ws = (float*)d_ws;
    const size_t SZ = (size_t)M_DIM * E_DIM;   // 8 Mi floats
    float* Qb = ws;
    float* Kb = ws + SZ;
    float* Vb = ws + 2 * SZ;
    float* Ob = ws + 3 * SZ;

    dim3 g1(M_DIM / 64, E_DIM / 64, 3);
    qkv_gemm<<<g1, 256, 0, stream>>>(x, Wq, bq, Wk, bk, Wv, bv, Qb, Kb, Vb);

    dim3 g2(S_DIM / 32, B_DIM * H_DIM);
    attn<<<g2, 256, 0, stream>>>(Qb, Kb, Vb, Ob);

    dim3 g3(M_DIM / 64, E_DIM / 64);
    out_gemm<<<g3, 256, 0, stream>>>(Ob, Wo, bo, (float*)d_out);
}

// Round 2
// 1346.381 us; speedup vs baseline: 2.5022x; 2.5022x over previous
//
#include <hip/hip_runtime.h>
#include <math.h>

#define E_DIM 1024
#define B_DIM 4
#define S_DIM 2048
#define H_DIM 16
#define D_HEAD 64
#define M_DIM (B_DIM * S_DIM)   // 8192

typedef _Float16 half8 __attribute__((ext_vector_type(8)));
typedef float floatx4 __attribute__((ext_vector_type(4)));
#define MFMA_F16(a, b, c) __builtin_amdgcn_mfma_f32_16x16x32_f16(a, b, c, 0, 0, 0)

// ---------------- QKV projection GEMM (fp32 compute, fp16 out) ----------------
__global__ __launch_bounds__(256) void qkv_gemm(
    const float* __restrict__ A,
    const float* __restrict__ Wq, const float* __restrict__ bq,
    const float* __restrict__ Wk, const float* __restrict__ bk,
    const float* __restrict__ Wv, const float* __restrict__ bv,
    _Float16* __restrict__ Qout, _Float16* __restrict__ Kout, _Float16* __restrict__ Vout)
{
    const int z = blockIdx.z;
    const float* W    = (z == 0) ? Wq : (z == 1) ? Wk : Wv;
    const float* bias = (z == 0) ? bq : (z == 1) ? bk : bv;
    _Float16* Out     = (z == 0) ? Qout : (z == 1) ? Kout : Vout;

    const int m0 = blockIdx.x * 64;
    const int n0 = blockIdx.y * 64;
    const int tid = threadIdx.x;
    const int tx = tid & 15, ty = tid >> 4;

    __shared__ float As[16][68];
    __shared__ float Bs[16][64];

    float c[4][4];
#pragma unroll
    for (int i = 0; i < 4; i++)
#pragma unroll
        for (int j = 0; j < 4; j++) c[i][j] = 0.f;

    for (int kc = 0; kc < E_DIM; kc += 16) {
#pragma unroll
        for (int r = 0; r < 4; r++) {
            int e = tid + r * 256;
            int row = e >> 4, col = e & 15;
            As[col][row] = A[(m0 + row) * E_DIM + kc + col];
        }
#pragma unroll
        for (int r = 0; r < 4; r++) {
            int e = tid + r * 256;
            int row = e >> 6, col = e & 63;
            Bs[row][col] = W[(kc + row) * E_DIM + n0 + col];
        }
        __syncthreads();
#pragma unroll
        for (int k = 0; k < 16; k++) {
            float4 av  = *(const float4*)&As[k][ty * 4];
            float4 bv4 = *(const float4*)&Bs[k][tx * 4];
            float a[4] = {av.x, av.y, av.z, av.w};
            float b[4] = {bv4.x, bv4.y, bv4.z, bv4.w};
#pragma unroll
            for (int i = 0; i < 4; i++)
#pragma unroll
                for (int j = 0; j < 4; j++) c[i][j] += a[i] * b[j];
        }
        __syncthreads();
    }

    const int h = n0 >> 6;
#pragma unroll
    for (int i = 0; i < 4; i++) {
        int m = m0 + ty * 4 + i;
        int b = m >> 11;
        int s = m & (S_DIM - 1);
#pragma unroll
        for (int j = 0; j < 4; j++) {
            int d = tx * 4 + j;
            Out[(((size_t)(b * H_DIM + h) * S_DIM) + s) * D_HEAD + d] =
                (_Float16)(c[i][j] + bias[n0 + d]);
        }
    }
}

// ---------------- Output projection GEMM (fp32) ----------------
__global__ __launch_bounds__(256) void out_gemm(
    const float* __restrict__ A, const float* __restrict__ W,
    const float* __restrict__ bias, float* __restrict__ Out)
{
    const int m0 = blockIdx.x * 64;
    const int n0 = blockIdx.y * 64;
    const int tid = threadIdx.x;
    const int tx = tid & 15, ty = tid >> 4;

    __shared__ float As[16][68];
    __shared__ float Bs[16][64];

    float c[4][4];
#pragma unroll
    for (int i = 0; i < 4; i++)
#pragma unroll
        for (int j = 0; j < 4; j++) c[i][j] = 0.f;

    for (int kc = 0; kc < E_DIM; kc += 16) {
#pragma unroll
        for (int r = 0; r < 4; r++) {
            int e = tid + r * 256;
            int row = e >> 4, col = e & 15;
            As[col][row] = A[(m0 + row) * E_DIM + kc + col];
        }
#pragma unroll
        for (int r = 0; r < 4; r++) {
            int e = tid + r * 256;
            int row = e >> 6, col = e & 63;
            Bs[row][col] = W[(kc + row) * E_DIM + n0 + col];
        }
        __syncthreads();
#pragma unroll
        for (int k = 0; k < 16; k++) {
            float4 av  = *(const float4*)&As[k][ty * 4];
            float4 bv4 = *(const float4*)&Bs[k][tx * 4];
            float a[4] = {av.x, av.y, av.z, av.w};
            float b[4] = {bv4.x, bv4.y, bv4.z, bv4.w};
#pragma unroll
            for (int i = 0; i < 4; i++)
#pragma unroll
                for (int j = 0; j < 4; j++) c[i][j] += a[i] * b[j];
        }
        __syncthreads();
    }

#pragma unroll
    for (int i = 0; i < 4; i++) {
        int m = m0 + ty * 4 + i;
#pragma unroll
        for (int j = 0; j < 4; j++) {
            int n = n0 + tx * 4 + j;
            Out[(size_t)m * E_DIM + n] = c[i][j] + bias[n];
        }
    }
}

// ---------------- MFMA causal flash attention ----------------
// Q,K,V fp16 in [B,H,S,D]; O fp32 in [B,S,E].
// Layouts (HW-verified, m89/m120): A[m=lane&15][k=quad*8+j], B[k=quad*8+j][n=lane&15],
// C/D: col=lane&15, row=quad*4+reg.
__global__ __launch_bounds__(256) void attn_mfma(
    const _Float16* __restrict__ Q, const _Float16* __restrict__ K,
    const _Float16* __restrict__ V, float* __restrict__ O)
{
    const int bh = blockIdx.y;
    const int q0 = blockIdx.x * 64;
    const int tid  = threadIdx.x;
    const int wave = tid >> 6;
    const int lane = tid & 63;
    const int m16  = lane & 15;
    const int quad = lane >> 4;
    const size_t base = (size_t)bh * S_DIM * D_HEAD;

    __shared__ _Float16 Qs[64 * 72];        // [q][d], stride 72 (144 B, 16B-mult)
    __shared__ _Float16 Ks[32 * 72];        // [key][d], stride 72
    __shared__ _Float16 Vt[64 * 40];        // [d][key-swizzled], stride 40 (80 B)
    __shared__ _Float16 Pb[4][16 * 48];     // per-wave P, [q][key], stride 48 (96 B)

    // stage Q tile (fp16, 16 B per thread per pass)
    for (int e = tid * 8; e < 64 * 64; e += 2048) {
        int r = e >> 6, c = e & 63;
        *(half8*)&Qs[r * 72 + c] = *(const half8*)&Q[base + (size_t)(q0 + r) * 64 + c];
    }
    __syncthreads();

    // Q fragments are loop-invariant: A[m=lane&15][k=quad*8+j], two K-dim halves
    half8 qf0 = *(const half8*)&Qs[(wave * 16 + m16) * 72 + quad * 8];
    half8 qf1 = *(const half8*)&Qs[(wave * 16 + m16) * 72 + 32 + quad * 8];

    float m_i[4], l_i[4];
    floatx4 accd[4];
    const floatx4 zf = {0.f, 0.f, 0.f, 0.f};
#pragma unroll
    for (int r = 0; r < 4; r++) { m_i[r] = -INFINITY; l_i[r] = 0.f; }
#pragma unroll
    for (int dt = 0; dt < 4; dt++) accd[dt] = zf;

    const int qi_base = q0 + wave * 16 + quad * 4;   // + reg -> global query row
    const int kmax = q0 + wave * 16 + 15;            // last key this wave needs

    for (int k0 = 0; k0 < q0 + 64; k0 += 32) {
        __syncthreads();   // previous chunk's readers done
        {
            // stage K chunk row-major; V chunk transposed with key-swizzle
            int e = tid * 8;
            int r = e >> 6, c = e & 63;             // key row, d base
            *(half8*)&Ks[r * 72 + c] = *(const half8*)&K[base + (size_t)(k0 + r) * 64 + c];
            half8 vv = *(const half8*)&V[base + (size_t)(k0 + r) * 64 + c];
#pragma unroll
            for (int j = 0; j < 8; j++) {
                int d = c + j;
                int s = (r + 8 * ((d >> 3) & 3)) & 31;   // bank swizzle on key index
                Vt[d * 40 + s] = vv[j];
            }
        }
        __syncthreads();

        if (k0 <= kmax) {
            // ---- scores: S[16q][32k] = Q·K^T, two 16-col tiles ----
            half8 k00 = *(const half8*)&Ks[m16 * 72 + quad * 8];
            half8 k01 = *(const half8*)&Ks[m16 * 72 + 32 + quad * 8];
            half8 k10 = *(const half8*)&Ks[(16 + m16) * 72 + quad * 8];
            half8 k11 = *(const half8*)&Ks[(16 + m16) * 72 + 32 + quad * 8];
            floatx4 s0v = MFMA_F16(qf0, k00, zf);
            s0v = MFMA_F16(qf1, k01, s0v);
            floatx4 s1v = MFMA_F16(qf0, k10, zf);
            s1v = MFMA_F16(qf1, k11, s1v);

            // ---- mask + scale + online softmax (rows live at quad*4+reg) ----
            float p0[4], p1[4], mc[4];
#pragma unroll
            for (int r = 0; r < 4; r++) {
                int qi = qi_base + r;
                p0[r] = (k0 + m16      <= qi) ? s0v[r] * 0.125f : -INFINITY;
                p1[r] = (k0 + 16 + m16 <= qi) ? s1v[r] * 0.125f : -INFINITY;
                mc[r] = fmaxf(p0[r], p1[r]);
            }
#pragma unroll
            for (int off = 8; off; off >>= 1)
#pragma unroll
                for (int r = 0; r < 4; r++)
                    mc[r] = fmaxf(mc[r], __shfl_xor(mc[r], off));

            float ladd[4];
#pragma unroll
            for (int r = 0; r < 4; r++) {
                float mn = fmaxf(m_i[r], mc[r]);        // finite after chunk 0
                float alpha = __expf(m_i[r] - mn);
                m_i[r] = mn;
                p0[r] = __expf(p0[r] - mn);
                p1[r] = __expf(p1[r] - mn);
                ladd[r] = p0[r] + p1[r];
                l_i[r] *= alpha;
#pragma unroll
                for (int dt = 0; dt < 4; dt++) accd[dt][r] *= alpha;
            }
#pragma unroll
            for (int off = 8; off; off >>= 1)
#pragma unroll
                for (int r = 0; r < 4; r++)
                    ladd[r] += __shfl_xor(ladd[r], off);
#pragma unroll
            for (int r = 0; r < 4; r++) l_i[r] += ladd[r];

            // ---- P: C-layout -> LDS -> A-layout (wave-local round trip) ----
            _Float16* pb = &Pb[wave][0];
#pragma unroll
            for (int r = 0; r < 4; r++) {
                int prow = quad * 4 + r;
                pb[prow * 48 + m16]      = (_Float16)p0[r];
                pb[prow * 48 + 16 + m16] = (_Float16)p1[r];
            }
            asm volatile("s_waitcnt lgkmcnt(0)" ::: "memory");
            half8 pf = *(const half8*)&pb[m16 * 48 + quad * 8];

            // ---- O += P·V, four 16-wide d tiles ----
#pragma unroll
            for (int dt = 0; dt < 4; dt++) {
                int d = dt * 16 + m16;
                int ro = ((quad + ((d >> 3) & 3)) & 3) * 8;   // undo key swizzle
                half8 vf = *(const half8*)&Vt[d * 40 + ro];
                accd[dt] = MFMA_F16(pf, vf, accd[dt]);
            }
        }
    }

    // ---- epilogue: normalize, write O in [B,S,E] ----
    const int b = bh >> 4;
    const int h = bh & (H_DIM - 1);
#pragma unroll
    for (int r = 0; r < 4; r++) {
        float inv = 1.f / l_i[r];
        int qrow = q0 + wave * 16 + quad * 4 + r;
        float* dst = O + (size_t)(b * S_DIM + qrow) * E_DIM + h * 64;
#pragma unroll
        for (int dt = 0; dt < 4; dt++)
            dst[dt * 16 + m16] = accd[dt][r] * inv;
    }
}

// ---------------- launch ----------------
extern "C" void kernel_launch(void* const* d_in, const int* in_sizes, int n_in,
                              void* d_out, int out_size, void* d_ws, size_t ws_size,
                              hipStream_t stream) {
    const float* x  = (const float*)d_in[0];
    const float* Wq = (const float*)d_in[1];
    const float* bq = (const float*)d_in[2];
    const float* Wk = (const float*)d_in[3];
    const float* bk = (const float*)d_in[4];
    const float* Wv = (const float*)d_in[5];
    const float* bv = (const float*)d_in[6];
    const float* Wo = (const float*)d_in[7];
    const float* bo = (const float*)d_in[8];

    const size_t SZ = (size_t)M_DIM * E_DIM;   // 8 Mi elements
    _Float16* Qh = (_Float16*)d_ws;
    _Float16* Kh = Qh + SZ;
    _Float16* Vh = Kh + SZ;
    float*    Ob = (float*)(Vh + SZ);          // 48 MB offset, 32 MB fp32

    dim3 g1(M_DIM / 64, E_DIM / 64, 3);
    qkv_gemm<<<g1, 256, 0, stream>>>(x, Wq, bq, Wk, bk, Wv, bv, Qh, Kh, Vh);

    dim3 g2(S_DIM / 64, B_DIM * H_DIM);
    attn_mfma<<<g2, 256, 0, stream>>>(Qh, Kh, Vh, Ob);

    dim3 g3(M_DIM / 64, E_DIM / 64);
    out_gemm<<<g3, 256, 0, stream>>>(Ob, Wo, bo, (float*)d_out);
}

// Round 3
// 533.374 us; speedup vs baseline: 6.3163x; 2.5243x over previous
//
#include <hip/hip_runtime.h>
#include <math.h>

#define E_DIM 1024
#define B_DIM 4
#define S_DIM 2048
#define H_DIM 16
#define D_HEAD 64
#define M_DIM (B_DIM * S_DIM)   // 8192

typedef _Float16 half8 __attribute__((ext_vector_type(8)));
typedef float floatx4 __attribute__((ext_vector_type(4)));
#define MFMA_F16(a, b, c) __builtin_amdgcn_mfma_f32_16x16x32_f16(a, b, c, 0, 0, 0)

// async global->LDS, 16B per lane; LDS dest = wave-uniform base + lane*16B
#define GLDS16(g, l)                                                          \
    __builtin_amdgcn_global_load_lds(                                         \
        (const __attribute__((address_space(1))) void*)(g),                   \
        (__attribute__((address_space(3))) void*)(l), 16, 0, 0)

// ---------------- x: fp32 -> fp16 cast copy ----------------
__global__ __launch_bounds__(256) void cvt_x(
    const float* __restrict__ X, _Float16* __restrict__ Xh)
{
    size_t i = ((size_t)blockIdx.x * 256 + threadIdx.x) * 8;
    float4 a = *(const float4*)&X[i];
    float4 b = *(const float4*)&X[i + 4];
    half8 h = {(_Float16)a.x, (_Float16)a.y, (_Float16)a.z, (_Float16)a.w,
               (_Float16)b.x, (_Float16)b.y, (_Float16)b.z, (_Float16)b.w};
    *(half8*)&Xh[i] = h;
}

// ---------------- W: fp32 [k][n] -> fp16 [n][k] transpose ----------------
__global__ __launch_bounds__(256) void cvt_w(
    const float* __restrict__ W0, const float* __restrict__ W1,
    const float* __restrict__ W2, const float* __restrict__ W3,
    _Float16* __restrict__ T0, _Float16* __restrict__ T1,
    _Float16* __restrict__ T2, _Float16* __restrict__ T3)
{
    const int z = blockIdx.z;
    const float* W = (z == 0) ? W0 : (z == 1) ? W1 : (z == 2) ? W2 : W3;
    _Float16*   T  = (z == 0) ? T0 : (z == 1) ? T1 : (z == 2) ? T2 : T3;
    const int k0 = blockIdx.x * 64, n0 = blockIdx.y * 64;
    const int tid = threadIdx.x;
    __shared__ float t[64][65];
#pragma unroll
    for (int it = 0; it < 4; it++) {
        int r = it * 16 + (tid >> 4);
        int c = (tid & 15) * 4;
        float4 v = *(const float4*)&W[(size_t)(k0 + r) * E_DIM + n0 + c];
        t[r][c] = v.x; t[r][c + 1] = v.y; t[r][c + 2] = v.z; t[r][c + 3] = v.w;
    }
    __syncthreads();
#pragma unroll
    for (int it = 0; it < 2; it++) {
        int n = it * 32 + (tid >> 3);
        int kk = (tid & 7) * 8;
        half8 h;
#pragma unroll
        for (int j = 0; j < 8; j++) h[j] = (_Float16)t[kk + j][n];
        *(half8*)&T[(size_t)(n0 + n) * E_DIM + k0 + kk] = h;
    }
}

// ---------------- MFMA GEMM core (m97 structure) ----------------
// A fp16 [M][1024] row-major; B fp16 [N][1024] (pre-transposed weights).
// 128x128 tile, 256 thr, 4 waves 2x2, each 4x4 of 16x16x32 MFMA. BK=32.
// LDS tiles [row][32] unpadded (64B rows) -- required by global_load_lds.
#define GEMM_CORE(Aptr, Bptr)                                                 \
    const int tid = threadIdx.x;                                              \
    const int wave = tid >> 6, lane = tid & 63;                               \
    const int m16 = lane & 15, quad = lane >> 4;                              \
    const int wm = (wave >> 1) * 64, wn = (wave & 1) * 64;                    \
    const int m0 = blockIdx.x * 128, n0 = blockIdx.y * 128;                   \
    __shared__ _Float16 As[128 * 32];                                         \
    __shared__ _Float16 Bs[128 * 32];                                         \
    floatx4 acc[4][4];                                                        \
    const floatx4 zf = {0.f, 0.f, 0.f, 0.f};                                  \
    _Pragma("unroll") for (int i = 0; i < 4; i++)                             \
        _Pragma("unroll") for (int j = 0; j < 4; j++) acc[i][j] = zf;         \
    const int lrow = lane >> 2, lseg = lane & 3;                              \
    const _Float16* gA = (Aptr) + (size_t)(m0 + wave * 32 + lrow) * E_DIM + lseg * 8; \
    const _Float16* gB = (Bptr) + (size_t)(n0 + wave * 32 + lrow) * E_DIM + lseg * 8; \
    _Float16* lA = As + (wave * 32) * 32;                                     \
    _Float16* lB = Bs + (wave * 32) * 32;                                     \
    for (int k0 = 0; k0 < E_DIM; k0 += 32) {                                  \
        __syncthreads();                                                      \
        GLDS16(gA + k0, lA);                                                  \
        GLDS16(gA + 16 * E_DIM + k0, lA + 16 * 32);                           \
        GLDS16(gB + k0, lB);                                                  \
        GLDS16(gB + 16 * E_DIM + k0, lB + 16 * 32);                           \
        __syncthreads();                                                      \
        half8 af[4], bf[4];                                                   \
        _Pragma("unroll") for (int mt = 0; mt < 4; mt++)                      \
            af[mt] = *(const half8*)&As[(wm + mt * 16 + m16) * 32 + quad * 8];\
        _Pragma("unroll") for (int nt = 0; nt < 4; nt++)                      \
            bf[nt] = *(const half8*)&Bs[(wn + nt * 16 + m16) * 32 + quad * 8];\
        _Pragma("unroll") for (int mt = 0; mt < 4; mt++)                      \
            _Pragma("unroll") for (int nt = 0; nt < 4; nt++)                  \
                acc[mt][nt] = MFMA_F16(af[mt], bf[nt], acc[mt][nt]);          \
    }

// QKV projection: epilogue scatters to [B,H,S,D] fp16
__global__ __launch_bounds__(256) void qkv_mfma(
    const _Float16* __restrict__ Xh,
    const _Float16* __restrict__ Tq, const float* __restrict__ bq,
    const _Float16* __restrict__ Tk, const float* __restrict__ bk,
    const _Float16* __restrict__ Tv, const float* __restrict__ bv,
    _Float16* __restrict__ Qo, _Float16* __restrict__ Ko, _Float16* __restrict__ Vo)
{
    const int z = blockIdx.z;
    const _Float16* Wt  = (z == 0) ? Tq : (z == 1) ? Tk : Tv;
    const float*    bias = (z == 0) ? bq : (z == 1) ? bk : bv;
    _Float16*       Out  = (z == 0) ? Qo : (z == 1) ? Ko : Vo;

    GEMM_CORE(Xh, Wt)

#pragma unroll
    for (int nt = 0; nt < 4; nt++) {
        int n = n0 + wn + nt * 16 + m16;
        int h = n >> 6, d = n & 63;
        float bv4 = bias[n];
#pragma unroll
        for (int mt = 0; mt < 4; mt++) {
#pragma unroll
            for (int r = 0; r < 4; r++) {
                int m = m0 + wm + mt * 16 + quad * 4 + r;
                int b = m >> 11, s = m & (S_DIM - 1);
                Out[(((size_t)(b * H_DIM + h) * S_DIM) + s) * D_HEAD + d] =
                    (_Float16)(acc[mt][nt][r] + bv4);
            }
        }
    }
}

// Output projection: A = O fp16 [M][E], epilogue writes fp32 [M][E]
__global__ __launch_bounds__(256) void out_mfma(
    const _Float16* __restrict__ Oh, const _Float16* __restrict__ To,
    const float* __restrict__ bias, float* __restrict__ Out)
{
    GEMM_CORE(Oh, To)

#pragma unroll
    for (int nt = 0; nt < 4; nt++) {
        int n = n0 + wn + nt * 16 + m16;
        float bv4 = bias[n];
#pragma unroll
        for (int mt = 0; mt < 4; mt++) {
#pragma unroll
            for (int r = 0; r < 4; r++) {
                int m = m0 + wm + mt * 16 + quad * 4 + r;
                Out[(size_t)m * E_DIM + n] = acc[mt][nt][r] + bv4;
            }
        }
    }
}

// ---------------- MFMA causal flash attention ----------------
// Q,K,V fp16 [B,H,S,D]; O fp16 [B,S,E].
__global__ __launch_bounds__(256) void attn_mfma(
    const _Float16* __restrict__ Q, const _Float16* __restrict__ K,
    const _Float16* __restrict__ V, _Float16* __restrict__ O)
{
    const int bh = blockIdx.y;
    const int q0 = blockIdx.x * 64;
    const int tid  = threadIdx.x;
    const int wave = tid >> 6;
    const int lane = tid & 63;
    const int m16  = lane & 15;
    const int quad = lane >> 4;
    const size_t base = (size_t)bh * S_DIM * D_HEAD;

    __shared__ _Float16 Qs[64 * 72];
    __shared__ _Float16 Ks[32 * 72];
    __shared__ _Float16 Vt[64 * 40];
    __shared__ _Float16 Pb[4][16 * 48];

    for (int e = tid * 8; e < 64 * 64; e += 2048) {
        int r = e >> 6, c = e & 63;
        *(half8*)&Qs[r * 72 + c] = *(const half8*)&Q[base + (size_t)(q0 + r) * 64 + c];
    }
    __syncthreads();

    half8 qf0 = *(const half8*)&Qs[(wave * 16 + m16) * 72 + quad * 8];
    half8 qf1 = *(const half8*)&Qs[(wave * 16 + m16) * 72 + 32 + quad * 8];

    float m_i[4], l_i[4];
    floatx4 accd[4];
    const floatx4 zf = {0.f, 0.f, 0.f, 0.f};
#pragma unroll
    for (int r = 0; r < 4; r++) { m_i[r] = -INFINITY; l_i[r] = 0.f; }
#pragma unroll
    for (int dt = 0; dt < 4; dt++) accd[dt] = zf;

    const int qi_base = q0 + wave * 16 + quad * 4;
    const int kmax = q0 + wave * 16 + 15;

    for (int k0 = 0; k0 < q0 + 64; k0 += 32) {
        __syncthreads();
        {
            int e = tid * 8;
            int r = e >> 6, c = e & 63;
            *(half8*)&Ks[r * 72 + c] = *(const half8*)&K[base + (size_t)(k0 + r) * 64 + c];
            half8 vv = *(const half8*)&V[base + (size_t)(k0 + r) * 64 + c];
#pragma unroll
            for (int j = 0; j < 8; j++) {
                int d = c + j;
                int s = (r + 8 * ((d >> 3) & 3)) & 31;
                Vt[d * 40 + s] = vv[j];
            }
        }
        __syncthreads();

        if (k0 <= kmax) {
            half8 k00 = *(const half8*)&Ks[m16 * 72 + quad * 8];
            half8 k01 = *(const half8*)&Ks[m16 * 72 + 32 + quad * 8];
            half8 k10 = *(const half8*)&Ks[(16 + m16) * 72 + quad * 8];
            half8 k11 = *(const half8*)&Ks[(16 + m16) * 72 + 32 + quad * 8];
            floatx4 s0v = MFMA_F16(qf0, k00, zf);
            s0v = MFMA_F16(qf1, k01, s0v);
            floatx4 s1v = MFMA_F16(qf0, k10, zf);
            s1v = MFMA_F16(qf1, k11, s1v);

            float p0[4], p1[4], mc[4];
#pragma unroll
            for (int r = 0; r < 4; r++) {
                int qi = qi_base + r;
                p0[r] = (k0 + m16      <= qi) ? s0v[r] * 0.125f : -INFINITY;
                p1[r] = (k0 + 16 + m16 <= qi) ? s1v[r] * 0.125f : -INFINITY;
                mc[r] = fmaxf(p0[r], p1[r]);
            }
#pragma unroll
            for (int off = 8; off; off >>= 1)
#pragma unroll
                for (int r = 0; r < 4; r++)
                    mc[r] = fmaxf(mc[r], __shfl_xor(mc[r], off));

            float ladd[4];
#pragma unroll
            for (int r = 0; r < 4; r++) {
                float mn = fmaxf(m_i[r], mc[r]);
                float alpha = __expf(m_i[r] - mn);
                m_i[r] = mn;
                p0[r] = __expf(p0[r] - mn);
                p1[r] = __expf(p1[r] - mn);
                ladd[r] = p0[r] + p1[r];
                l_i[r] *= alpha;
#pragma unroll
                for (int dt = 0; dt < 4; dt++) accd[dt][r] *= alpha;
            }
#pragma unroll
            for (int off = 8; off; off >>= 1)
#pragma unroll
                for (int r = 0; r < 4; r++)
                    ladd[r] += __shfl_xor(ladd[r], off);
#pragma unroll
            for (int r = 0; r < 4; r++) l_i[r] += ladd[r];

            _Float16* pb = &Pb[wave][0];
#pragma unroll
            for (int r = 0; r < 4; r++) {
                int prow = quad * 4 + r;
                pb[prow * 48 + m16]      = (_Float16)p0[r];
                pb[prow * 48 + 16 + m16] = (_Float16)p1[r];
            }
            asm volatile("s_waitcnt lgkmcnt(0)" ::: "memory");
            half8 pf = *(const half8*)&pb[m16 * 48 + quad * 8];

#pragma unroll
            for (int dt = 0; dt < 4; dt++) {
                int d = dt * 16 + m16;
                int ro = ((quad + ((d >> 3) & 3)) & 3) * 8;
                half8 vf = *(const half8*)&Vt[d * 40 + ro];
                accd[dt] = MFMA_F16(pf, vf, accd[dt]);
            }
        }
    }

    const int b = bh >> 4;
    const int h = bh & (H_DIM - 1);
#pragma unroll
    for (int r = 0; r < 4; r++) {
        float inv = 1.f / l_i[r];
        int qrow = q0 + wave * 16 + quad * 4 + r;
        _Float16* dst = O + (size_t)(b * S_DIM + qrow) * E_DIM + h * 64;
#pragma unroll
        for (int dt = 0; dt < 4; dt++)
            dst[dt * 16 + m16] = (_Float16)(accd[dt][r] * inv);
    }
}

// ---------------- launch ----------------
extern "C" void kernel_launch(void* const* d_in, const int* in_sizes, int n_in,
                              void* d_out, int out_size, void* d_ws, size_t ws_size,
                              hipStream_t stream) {
    const float* x  = (const float*)d_in[0];
    const float* Wq = (const float*)d_in[1];
    const float* bq = (const float*)d_in[2];
    const float* Wk = (const float*)d_in[3];
    const float* bk = (const float*)d_in[4];
    const float* Wv = (const float*)d_in[5];
    const float* bv = (const float*)d_in[6];
    const float* Wo = (const float*)d_in[7];
    const float* bo = (const float*)d_in[8];

    const size_t SZ = (size_t)M_DIM * E_DIM;   // 8 Mi elements
    const size_t WZ = (size_t)E_DIM * E_DIM;   // 1 Mi elements
    _Float16* Xh = (_Float16*)d_ws;            // 16 MB (later reused as Oh)
    _Float16* Tq = Xh + SZ;                    // 2 MB each
    _Float16* Tk = Tq + WZ;
    _Float16* Tv = Tk + WZ;
    _Float16* To = Tv + WZ;
    _Float16* Qh = To + WZ;                    // 16 MB each
    _Float16* Kh = Qh + SZ;
    _Float16* Vh = Kh + SZ;
    _Float16* Oh = Xh;                         // alias: x dead after qkv_mfma

    cvt_x<<<dim3(M_DIM * E_DIM / 2048), 256, 0, stream>>>(x, Xh);
    cvt_w<<<dim3(16, 16, 4), 256, 0, stream>>>(Wq, Wk, Wv, Wo, Tq, Tk, Tv, To);

    qkv_mfma<<<dim3(M_DIM / 128, E_DIM / 128, 3), 256, 0, stream>>>(
        Xh, Tq, bq, Tk, bk, Tv, bv, Qh, Kh, Vh);

    attn_mfma<<<dim3(S_DIM / 64, B_DIM * H_DIM), 256, 0, stream>>>(Qh, Kh, Vh, Oh);

    out_mfma<<<dim3(M_DIM / 128, E_DIM / 128), 256, 0, stream>>>(
        Oh, To, bo, (float*)d_out);
}

// Round 4
// 442.491 us; speedup vs baseline: 7.6137x; 1.2054x over previous
//
#include <hip/hip_runtime.h>
#include <math.h>

#define E_DIM 1024
#define B_DIM 4
#define S_DIM 2048
#define H_DIM 16
#define D_HEAD 64
#define M_DIM (B_DIM * S_DIM)   // 8192

typedef _Float16 half8 __attribute__((ext_vector_type(8)));
typedef _Float16 half4 __attribute__((ext_vector_type(4)));
typedef float floatx4 __attribute__((ext_vector_type(4)));
#define MFMA_F16(a, b, c) __builtin_amdgcn_mfma_f32_16x16x32_f16(a, b, c, 0, 0, 0)

// async global->LDS, 16B per lane; LDS dest = wave-uniform base + lane*16B
#define GLDS16(g, l)                                                          \
    __builtin_amdgcn_global_load_lds(                                         \
        (const __attribute__((address_space(1))) void*)(g),                   \
        (__attribute__((address_space(3))) void*)(l), 16, 0, 0)

// ---------------- x: fp32 -> fp16 cast copy ----------------
__global__ __launch_bounds__(256) void cvt_x(
    const float* __restrict__ X, _Float16* __restrict__ Xh)
{
    size_t i = ((size_t)blockIdx.x * 256 + threadIdx.x) * 8;
    float4 a = *(const float4*)&X[i];
    float4 b = *(const float4*)&X[i + 4];
    half8 h = {(_Float16)a.x, (_Float16)a.y, (_Float16)a.z, (_Float16)a.w,
               (_Float16)b.x, (_Float16)b.y, (_Float16)b.z, (_Float16)b.w};
    *(half8*)&Xh[i] = h;
}

// ---------------- W: fp32 [k][n] -> fp16 [n][k] transpose ----------------
__global__ __launch_bounds__(256) void cvt_w(
    const float* __restrict__ W0, const float* __restrict__ W1,
    const float* __restrict__ W2, const float* __restrict__ W3,
    _Float16* __restrict__ T0, _Float16* __restrict__ T1,
    _Float16* __restrict__ T2, _Float16* __restrict__ T3)
{
    const int z = blockIdx.z;
    const float* W = (z == 0) ? W0 : (z == 1) ? W1 : (z == 2) ? W2 : W3;
    _Float16*   T  = (z == 0) ? T0 : (z == 1) ? T1 : (z == 2) ? T2 : T3;
    const int k0 = blockIdx.x * 64, n0 = blockIdx.y * 64;
    const int tid = threadIdx.x;
    __shared__ float t[64][65];
#pragma unroll
    for (int it = 0; it < 4; it++) {
        int r = it * 16 + (tid >> 4);
        int c = (tid & 15) * 4;
        float4 v = *(const float4*)&W[(size_t)(k0 + r) * E_DIM + n0 + c];
        t[r][c] = v.x; t[r][c + 1] = v.y; t[r][c + 2] = v.z; t[r][c + 3] = v.w;
    }
    __syncthreads();
#pragma unroll
    for (int it = 0; it < 2; it++) {
        int n = it * 32 + (tid >> 3);
        int kk = (tid & 7) * 8;
        half8 h;
#pragma unroll
        for (int j = 0; j < 8; j++) h[j] = (_Float16)t[kk + j][n];
        *(half8*)&T[(size_t)(n0 + n) * E_DIM + k0 + kk] = h;
    }
}

// ---------------- MFMA GEMM core (m97 structure) ----------------
#define GEMM_CORE(Aptr, Bptr)                                                 \
    const int tid = threadIdx.x;                                              \
    const int wave = tid >> 6, lane = tid & 63;                               \
    const int m16 = lane & 15, quad = lane >> 4;                              \
    const int wm = (wave >> 1) * 64, wn = (wave & 1) * 64;                    \
    const int m0 = blockIdx.x * 128, n0 = blockIdx.y * 128;                   \
    __shared__ _Float16 As[128 * 32];                                         \
    __shared__ _Float16 Bs[128 * 32];                                         \
    floatx4 acc[4][4];                                                        \
    const floatx4 zf = {0.f, 0.f, 0.f, 0.f};                                  \
    _Pragma("unroll") for (int i = 0; i < 4; i++)                             \
        _Pragma("unroll") for (int j = 0; j < 4; j++) acc[i][j] = zf;         \
    const int lrow = lane >> 2, lseg = lane & 3;                              \
    const _Float16* gA = (Aptr) + (size_t)(m0 + wave * 32 + lrow) * E_DIM + lseg * 8; \
    const _Float16* gB = (Bptr) + (size_t)(n0 + wave * 32 + lrow) * E_DIM + lseg * 8; \
    _Float16* lA = As + (wave * 32) * 32;                                     \
    _Float16* lB = Bs + (wave * 32) * 32;                                     \
    for (int k0 = 0; k0 < E_DIM; k0 += 32) {                                  \
        __syncthreads();                                                      \
        GLDS16(gA + k0, lA);                                                  \
        GLDS16(gA + 16 * E_DIM + k0, lA + 16 * 32);                           \
        GLDS16(gB + k0, lB);                                                  \
        GLDS16(gB + 16 * E_DIM + k0, lB + 16 * 32);                           \
        __syncthreads();                                                      \
        half8 af[4], bf[4];                                                   \
        _Pragma("unroll") for (int mt = 0; mt < 4; mt++)                      \
            af[mt] = *(const half8*)&As[(wm + mt * 16 + m16) * 32 + quad * 8];\
        _Pragma("unroll") for (int nt = 0; nt < 4; nt++)                      \
            bf[nt] = *(const half8*)&Bs[(wn + nt * 16 + m16) * 32 + quad * 8];\
        _Pragma("unroll") for (int mt = 0; mt < 4; mt++)                      \
            _Pragma("unroll") for (int nt = 0; nt < 4; nt++)                  \
                acc[mt][nt] = MFMA_F16(af[mt], bf[nt], acc[mt][nt]);          \
    }

// QKV projection. z=0: Q scatter [B,H,S,D] pre-scaled by 0.125; z=1: K scatter;
// z=2: V written as per-(bh,64-chunk) 8KB blobs matching attn's LDS image:
//   elem off = bh*131072 + c*4096 + kh*2048 + dt*512 + (qv*16 + (d&15))*8 + (s&7)
//   where c=s>>6, kh=(s>>5)&1, qv=(s>>3)&3, dt=d>>4.
__global__ __launch_bounds__(256) void qkv_mfma(
    const _Float16* __restrict__ Xh,
    const _Float16* __restrict__ Tq, const float* __restrict__ bq,
    const _Float16* __restrict__ Tk, const float* __restrict__ bk,
    const _Float16* __restrict__ Tv, const float* __restrict__ bv,
    _Float16* __restrict__ Qo, _Float16* __restrict__ Ko, _Float16* __restrict__ Vo)
{
    const int z = blockIdx.z;
    const _Float16* Wt   = (z == 0) ? Tq : (z == 1) ? Tk : Tv;
    const float*    bias = (z == 0) ? bq : (z == 1) ? bk : bv;

    GEMM_CORE(Xh, Wt)

    if (z == 2) {
        const int m_base = m0 + wm;                      // multiple of 64
        const int b  = m_base >> 11;
        const int h  = (n0 + wn) >> 6;
        const int bh = b * H_DIM + h;
        const int c  = (m_base >> 6) & 31;
        const size_t cbase = (size_t)bh * 131072 + (size_t)c * 4096;
        const int e0 = (quad & 1) * 4;
#pragma unroll
        for (int mt = 0; mt < 4; mt++) {
            int kh = mt >> 1;
            int qv = ((mt & 1) * 2) + (quad >> 1);
#pragma unroll
            for (int nt = 0; nt < 4; nt++) {
                float bias_v = bias[n0 + wn + nt * 16 + m16];
                size_t off = cbase + (size_t)kh * 2048 + nt * 512 + (qv * 16 + m16) * 8 + e0;
                half4 hv;
#pragma unroll
                for (int r = 0; r < 4; r++) hv[r] = (_Float16)(acc[mt][nt][r] + bias_v);
                *(half4*)&Vo[off] = hv;
            }
        }
    } else {
        _Float16* Out = (z == 0) ? Qo : Ko;
        const float sc = (z == 0) ? 0.125f : 1.0f;       // fold 1/sqrt(D) into Q
#pragma unroll
        for (int nt = 0; nt < 4; nt++) {
            int n = n0 + wn + nt * 16 + m16;
            int h = n >> 6, d = n & 63;
            float bias_v = bias[n];
#pragma unroll
            for (int mt = 0; mt < 4; mt++) {
#pragma unroll
                for (int r = 0; r < 4; r++) {
                    int m = m0 + wm + mt * 16 + quad * 4 + r;
                    int b = m >> 11, s = m & (S_DIM - 1);
                    Out[(((size_t)(b * H_DIM + h) * S_DIM) + s) * D_HEAD + d] =
                        (_Float16)((acc[mt][nt][r] + bias_v) * sc);
                }
            }
        }
    }
}

// Output projection: A = O fp16 [M][E], writes fp32 [M][E]
__global__ __launch_bounds__(256) void out_mfma(
    const _Float16* __restrict__ Oh, const _Float16* __restrict__ To,
    const float* __restrict__ bias, float* __restrict__ Out)
{
    GEMM_CORE(Oh, To)

#pragma unroll
    for (int nt = 0; nt < 4; nt++) {
        int n = n0 + wn + nt * 16 + m16;
        float bias_v = bias[n];
#pragma unroll
        for (int mt = 0; mt < 4; mt++) {
#pragma unroll
            for (int r = 0; r < 4; r++) {
                int m = m0 + wm + mt * 16 + quad * 4 + r;
                Out[(size_t)m * E_DIM + n] = acc[mt][nt][r] + bias_v;
            }
        }
    }
}

// ---------------- MFMA causal flash attention ----------------
// 128 queries/block (4 waves x 32q), 64-key chunks. Q pre-scaled by 1/8.
// K [B,H,S,D]; V in blob layout; O fp16 [B,S,E]. All staging via global_load_lds.
__global__ __launch_bounds__(256) void attn_mfma(
    const _Float16* __restrict__ Q, const _Float16* __restrict__ K,
    const _Float16* __restrict__ Vb, _Float16* __restrict__ O)
{
    const int bh = blockIdx.y;
    const int q0 = (int)(gridDim.x - 1 - blockIdx.x) * 128;   // heavy blocks first
    const int tid = threadIdx.x;
    const int wave = tid >> 6, lane = tid & 63;
    const int m16 = lane & 15, quad = lane >> 4;
    const size_t base = (size_t)bh * S_DIM * D_HEAD;

    __shared__ _Float16 QP[9216];   // Q staging [128][64] (8192), then per-wave P [32][72]
    __shared__ _Float16 Ks[4096];   // [key][64] unpadded
    __shared__ _Float16 Vs[4096];   // blob image: [kh][dt][u][8]

    // stage Q (16 KB, linear)
    const _Float16* gQ = Q + base + (size_t)q0 * 64;
#pragma unroll
    for (int t = 0; t < 4; t++) {
        int i = wave * 4 + t;
        GLDS16(gQ + i * 512 + lane * 8, QP + i * 512);
    }
    __syncthreads();

    // loop-invariant Q fragments: A[m=m16][k=quad*8+j], 2 q-tiles x 2 d-halves
    half8 qf[2][2];
#pragma unroll
    for (int mt = 0; mt < 2; mt++)
#pragma unroll
        for (int dh = 0; dh < 2; dh++)
            qf[mt][dh] = *(const half8*)&QP[(wave * 32 + mt * 16 + m16) * 64 + dh * 32 + quad * 8];

    float m_i[2][4], l_i[2][4];
    floatx4 accd[2][4];
    const floatx4 zf = {0.f, 0.f, 0.f, 0.f};
#pragma unroll
    for (int mt = 0; mt < 2; mt++)
#pragma unroll
        for (int r = 0; r < 4; r++) { m_i[mt][r] = -INFINITY; l_i[mt][r] = 0.f; }
#pragma unroll
    for (int mt = 0; mt < 2; mt++)
#pragma unroll
        for (int dt = 0; dt < 4; dt++) accd[mt][dt] = zf;

    _Float16* Pw = QP + wave * 2304;
    const int qb0 = q0 + wave * 32 + quad * 4;
    const int qb1 = qb0 + 16;
    const int qmax = q0 + wave * 32 + 31;
    const _Float16* gK = K + base;
    const _Float16* gV = Vb + (size_t)bh * 131072;

    for (int k0 = 0; k0 < q0 + 128; k0 += 64) {
        __syncthreads();   // previous compute done (iter0: Q-frag reads drained)
        {
            int i = wave * 2;
            const _Float16* ks = gK + (size_t)k0 * 64;
            const _Float16* vs = gV + (size_t)(k0 >> 6) * 4096;
            GLDS16(ks + i * 512 + lane * 8, Ks + i * 512);
            GLDS16(ks + (i + 1) * 512 + lane * 8, Ks + (i + 1) * 512);
            GLDS16(vs + i * 512 + lane * 8, Vs + i * 512);
            GLDS16(vs + (i + 1) * 512 + lane * 8, Vs + (i + 1) * 512);
        }
        __syncthreads();
        if (k0 > qmax) continue;   // wave fully masked; barriers already passed

        // ---- QK^T: 16 MFMAs ----
        floatx4 sf[2][4];
#pragma unroll
        for (int kt = 0; kt < 4; kt++) {
            half8 kf0 = *(const half8*)&Ks[(kt * 16 + m16) * 64 + quad * 8];
            half8 kf1 = *(const half8*)&Ks[(kt * 16 + m16) * 64 + 32 + quad * 8];
#pragma unroll
            for (int mt = 0; mt < 2; mt++) {
                floatx4 t = MFMA_F16(qf[mt][0], kf0, zf);
                sf[mt][kt] = MFMA_F16(qf[mt][1], kf1, t);
            }
        }

        // ---- online softmax (Q already carries 1/8 scale) ----
#pragma unroll
        for (int mt = 0; mt < 2; mt++) {
            const int qbm = mt ? qb1 : qb0;
            float p[4][4], mc[4], alpha[4], ladd[4];
#pragma unroll
            for (int r = 0; r < 4; r++) mc[r] = -INFINITY;
#pragma unroll
            for (int kt = 0; kt < 4; kt++) {
                int key = k0 + kt * 16 + m16;
#pragma unroll
                for (int r = 0; r < 4; r++) {
                    p[kt][r] = (key <= qbm + r) ? sf[mt][kt][r] : -INFINITY;
                    mc[r] = fmaxf(mc[r], p[kt][r]);
                }
            }
#pragma unroll
            for (int off = 8; off; off >>= 1)
#pragma unroll
                for (int r = 0; r < 4; r++)
                    mc[r] = fmaxf(mc[r], __shfl_xor(mc[r], off));
#pragma unroll
            for (int r = 0; r < 4; r++) {
                float mn = fmaxf(m_i[mt][r], mc[r]);
                alpha[r] = __expf(m_i[mt][r] - mn);
                m_i[mt][r] = mn;
                float la = 0.f;
#pragma unroll
                for (int kt = 0; kt < 4; kt++) {
                    float e = __expf(p[kt][r] - mn);
                    p[kt][r] = e;
                    la += e;
                }
                ladd[r] = la;
#pragma unroll
                for (int dt = 0; dt < 4; dt++) accd[mt][dt][r] *= alpha[r];
            }
#pragma unroll
            for (int off = 8; off; off >>= 1)
#pragma unroll
                for (int r = 0; r < 4; r++)
                    ladd[r] += __shfl_xor(ladd[r], off);
#pragma unroll
            for (int r = 0; r < 4; r++)
                l_i[mt][r] = l_i[mt][r] * alpha[r] + ladd[r];

            // P: C-layout -> wave-local LDS (A-layout source)
#pragma unroll
            for (int kt = 0; kt < 4; kt++)
#pragma unroll
                for (int r = 0; r < 4; r++)
                    Pw[(mt * 16 + quad * 4 + r) * 72 + kt * 16 + m16] = (_Float16)p[kt][r];
        }
        asm volatile("s_waitcnt lgkmcnt(0)" ::: "memory");

        // ---- P·V: 16 MFMAs ----
        half8 pf[2][2];
#pragma unroll
        for (int mt = 0; mt < 2; mt++)
#pragma unroll
            for (int kh = 0; kh < 2; kh++)
                pf[mt][kh] = *(const half8*)&Pw[(mt * 16 + m16) * 72 + kh * 32 + quad * 8];
#pragma unroll
        for (int dt = 0; dt < 4; dt++) {
            half8 v0 = *(const half8*)&Vs[dt * 512 + (quad * 16 + m16) * 8];
            half8 v1 = *(const half8*)&Vs[2048 + dt * 512 + (quad * 16 + m16) * 8];
#pragma unroll
            for (int mt = 0; mt < 2; mt++)
                accd[mt][dt] = MFMA_F16(pf[mt][1], v1, MFMA_F16(pf[mt][0], v0, accd[mt][dt]));
        }
    }

    // ---- epilogue: normalize, write O fp16 [B,S,E] ----
    const int b = bh >> 4;
    const int h = bh & (H_DIM - 1);
#pragma unroll
    for (int mt = 0; mt < 2; mt++) {
#pragma unroll
        for (int r = 0; r < 4; r++) {
            float inv = 1.f / l_i[mt][r];
            int row = q0 + wave * 32 + mt * 16 + quad * 4 + r;
            _Float16* dst = O + (size_t)(b * S_DIM + row) * E_DIM + h * 64;
#pragma unroll
            for (int dt = 0; dt < 4; dt++)
                dst[dt * 16 + m16] = (_Float16)(accd[mt][dt][r] * inv);
        }
    }
}

// ---------------- launch ----------------
extern "C" void kernel_launch(void* const* d_in, const int* in_sizes, int n_in,
                              void* d_out, int out_size, void* d_ws, size_t ws_size,
                              hipStream_t stream) {
    const float* x  = (const float*)d_in[0];
    const float* Wq = (const float*)d_in[1];
    const float* bq = (const float*)d_in[2];
    const float* Wk = (const float*)d_in[3];
    const float* bk = (const float*)d_in[4];
    const float* Wv = (const float*)d_in[5];
    const float* bv = (const float*)d_in[6];
    const float* Wo = (const float*)d_in[7];
    const float* bo = (const float*)d_in[8];

    const size_t SZ = (size_t)M_DIM * E_DIM;   // 8 Mi elements
    const size_t WZ = (size_t)E_DIM * E_DIM;
    _Float16* Xh = (_Float16*)d_ws;            // 16 MB (reused as Oh)
    _Float16* Tq = Xh + SZ;
    _Float16* Tk = Tq + WZ;
    _Float16* Tv = Tk + WZ;
    _Float16* To = Tv + WZ;
    _Float16* Qh = To + WZ;
    _Float16* Kh = Qh + SZ;
    _Float16* Vb = Kh + SZ;                    // V blob, 16 MB
    _Float16* Oh = Xh;                         // alias: x dead after qkv_mfma

    cvt_x<<<dim3(M_DIM * E_DIM / 2048), 256, 0, stream>>>(x, Xh);
    cvt_w<<<dim3(16, 16, 4), 256, 0, stream>>>(Wq, Wk, Wv, Wo, Tq, Tk, Tv, To);

    qkv_mfma<<<dim3(M_DIM / 128, E_DIM / 128, 3), 256, 0, stream>>>(
        Xh, Tq, bq, Tk, bk, Tv, bv, Qh, Kh, Vb);

    attn_mfma<<<dim3(S_DIM / 128, B_DIM * H_DIM), 256, 0, stream>>>(Qh, Kh, Vb, Oh);

    out_mfma<<<dim3(M_DIM / 128, E_DIM / 128), 256, 0, stream>>>(
        Oh, To, bo, (float*)d_out);
}

// Round 5
// 329.134 us; speedup vs baseline: 10.2359x; 1.3444x over previous
//
#include <hip/hip_runtime.h>
#include <math.h>

#define E_DIM 1024
#define B_DIM 4
#define S_DIM 2048
#define H_DIM 16
#define D_HEAD 64
#define M_DIM (B_DIM * S_DIM)   // 8192

typedef _Float16 half8 __attribute__((ext_vector_type(8)));
typedef _Float16 half4 __attribute__((ext_vector_type(4)));
typedef float floatx4 __attribute__((ext_vector_type(4)));
#define MFMA_F16(a, b, c) __builtin_amdgcn_mfma_f32_16x16x32_f16(a, b, c, 0, 0, 0)

// async global->LDS, 16B per lane; LDS dest = wave-uniform base + lane*16B
#define GLDS16(g, l)                                                          \
    __builtin_amdgcn_global_load_lds(                                         \
        (const __attribute__((address_space(1))) void*)(g),                   \
        (__attribute__((address_space(3))) void*)(l), 16, 0, 0)

// ---------------- x: fp32 -> fp16 cast copy ----------------
__global__ __launch_bounds__(256) void cvt_x(
    const float* __restrict__ X, _Float16* __restrict__ Xh)
{
    size_t i = ((size_t)blockIdx.x * 256 + threadIdx.x) * 8;
    float4 a = *(const float4*)&X[i];
    float4 b = *(const float4*)&X[i + 4];
    half8 h = {(_Float16)a.x, (_Float16)a.y, (_Float16)a.z, (_Float16)a.w,
               (_Float16)b.x, (_Float16)b.y, (_Float16)b.z, (_Float16)b.w};
    *(half8*)&Xh[i] = h;
}

// ---------------- W: fp32 [k][n] -> fp16 [n][k] transpose ----------------
__global__ __launch_bounds__(256) void cvt_w(
    const float* __restrict__ W0, const float* __restrict__ W1,
    const float* __restrict__ W2, const float* __restrict__ W3,
    _Float16* __restrict__ T0, _Float16* __restrict__ T1,
    _Float16* __restrict__ T2, _Float16* __restrict__ T3)
{
    const int z = blockIdx.z;
    const float* W = (z == 0) ? W0 : (z == 1) ? W1 : (z == 2) ? W2 : W3;
    _Float16*   T  = (z == 0) ? T0 : (z == 1) ? T1 : (z == 2) ? T2 : T3;
    const int k0 = blockIdx.x * 64, n0 = blockIdx.y * 64;
    const int tid = threadIdx.x;
    __shared__ float t[64][65];
#pragma unroll
    for (int it = 0; it < 4; it++) {
        int r = it * 16 + (tid >> 4);
        int c = (tid & 15) * 4;
        float4 v = *(const float4*)&W[(size_t)(k0 + r) * E_DIM + n0 + c];
        t[r][c] = v.x; t[r][c + 1] = v.y; t[r][c + 2] = v.z; t[r][c + 3] = v.w;
    }
    __syncthreads();
#pragma unroll
    for (int it = 0; it < 2; it++) {
        int n = it * 32 + (tid >> 3);
        int kk = (tid & 7) * 8;
        half8 h;
#pragma unroll
        for (int j = 0; j < 8; j++) h[j] = (_Float16)t[kk + j][n];
        *(half8*)&T[(size_t)(n0 + n) * E_DIM + k0 + kk] = h;
    }
}

// ---------------- MFMA GEMM core (m97 structure) ----------------
#define GEMM_CORE(Aptr, Bptr)                                                 \
    const int tid = threadIdx.x;                                              \
    const int wave = tid >> 6, lane = tid & 63;                               \
    const int m16 = lane & 15, quad = lane >> 4;                              \
    const int wm = (wave >> 1) * 64, wn = (wave & 1) * 64;                    \
    const int m0 = blockIdx.x * 128, n0 = blockIdx.y * 128;                   \
    __shared__ _Float16 As[128 * 32];                                         \
    __shared__ _Float16 Bs[128 * 32];                                         \
    floatx4 acc[4][4];                                                        \
    const floatx4 zf = {0.f, 0.f, 0.f, 0.f};                                  \
    _Pragma("unroll") for (int i = 0; i < 4; i++)                             \
        _Pragma("unroll") for (int j = 0; j < 4; j++) acc[i][j] = zf;         \
    const int lrow = lane >> 2, lseg = lane & 3;                              \
    const _Float16* gA = (Aptr) + (size_t)(m0 + wave * 32 + lrow) * E_DIM + lseg * 8; \
    const _Float16* gB = (Bptr) + (size_t)(n0 + wave * 32 + lrow) * E_DIM + lseg * 8; \
    _Float16* lA = As + (wave * 32) * 32;                                     \
    _Float16* lB = Bs + (wave * 32) * 32;                                     \
    for (int k0 = 0; k0 < E_DIM; k0 += 32) {                                  \
        __syncthreads();                                                      \
        GLDS16(gA + k0, lA);                                                  \
        GLDS16(gA + 16 * E_DIM + k0, lA + 16 * 32);                           \
        GLDS16(gB + k0, lB);                                                  \
        GLDS16(gB + 16 * E_DIM + k0, lB + 16 * 32);                           \
        __syncthreads();                                                      \
        half8 af[4], bf[4];                                                   \
        _Pragma("unroll") for (int mt = 0; mt < 4; mt++)                      \
            af[mt] = *(const half8*)&As[(wm + mt * 16 + m16) * 32 + quad * 8];\
        _Pragma("unroll") for (int nt = 0; nt < 4; nt++)                      \
            bf[nt] = *(const half8*)&Bs[(wn + nt * 16 + m16) * 32 + quad * 8];\
        _Pragma("unroll") for (int mt = 0; mt < 4; mt++)                      \
            _Pragma("unroll") for (int nt = 0; nt < 4; nt++)                  \
                acc[mt][nt] = MFMA_F16(af[mt], bf[nt], acc[mt][nt]);          \
    }

// QKV projection epilogues write bank-swizzled blobs (16B block db ^ (row&7)):
//  Q blob: per (bh,qblk128): [q][d]  off = q*64 + ((d>>3)^(q&7))*8 + (d&7), Q pre-scaled 1/8
//  K blob: per (bh,kc64):    [k][d]  off = k*64 + ((d>>3)^(k&7))*8 + (d&7)
//  V blob: per (bh,kc64): V^T [d][k] off = d*64 + ((k>>3)^(d&7))*8 + (k&7)
__global__ __launch_bounds__(256) void qkv_mfma(
    const _Float16* __restrict__ Xh,
    const _Float16* __restrict__ Tq, const float* __restrict__ bq,
    const _Float16* __restrict__ Tk, const float* __restrict__ bk,
    const _Float16* __restrict__ Tv, const float* __restrict__ bv,
    _Float16* __restrict__ Qo, _Float16* __restrict__ Ko, _Float16* __restrict__ Vo)
{
    const int z = blockIdx.z;
    const _Float16* Wt   = (z == 0) ? Tq : (z == 1) ? Tk : Tv;
    const float*    bias = (z == 0) ? bq : (z == 1) ? bk : bv;

    GEMM_CORE(Xh, Wt)

    if (z == 2) {
        // V^T blob: for fixed (mt,nt) the 4 acc regs are 4 consecutive keys -> half4
#pragma unroll
        for (int nt = 0; nt < 4; nt++) {
            int n = n0 + wn + nt * 16 + m16;
            int h = n >> 6, d = n & 63, d7 = n & 7;
            float bias_v = bias[n];
#pragma unroll
            for (int mt = 0; mt < 4; mt++) {
                int m_b = m0 + wm + mt * 16 + quad * 4;
                int b = m_b >> 11, s = m_b & 2047;
                int bh = b * H_DIM + h;
                size_t off = ((size_t)bh * 32 + (s >> 6)) * 4096
                           + (size_t)d * 64 + ((((s >> 3) & 7) ^ d7) * 8) + (s & 7);
                half4 hv;
#pragma unroll
                for (int r = 0; r < 4; r++) hv[r] = (_Float16)(acc[mt][nt][r] + bias_v);
                *(half4*)&Vo[off] = hv;
            }
        }
    } else {
        _Float16* Out = (z == 0) ? Qo : Ko;
        const float sc = (z == 0) ? 0.125f : 1.0f;   // fold 1/sqrt(D) into Q
#pragma unroll
        for (int nt = 0; nt < 4; nt++) {
            int n = n0 + wn + nt * 16 + m16;
            int h = n >> 6;
            int db = (n >> 3) & 7, d7 = n & 7;
            float bias_v = bias[n];
#pragma unroll
            for (int mt = 0; mt < 4; mt++) {
#pragma unroll
                for (int r = 0; r < 4; r++) {
                    int m = m0 + wm + mt * 16 + quad * 4 + r;
                    int b = m >> 11, s = m & 2047;
                    int bh = b * H_DIM + h;
                    size_t off;
                    if (z == 0)
                        off = ((size_t)bh * 16 + (s >> 7)) * 8192
                            + (size_t)(s & 127) * 64 + ((db ^ (s & 7)) * 8) + d7;
                    else
                        off = ((size_t)bh * 32 + (s >> 6)) * 4096
                            + (size_t)(s & 63) * 64 + ((db ^ (s & 7)) * 8) + d7;
                    Out[off] = (_Float16)((acc[mt][nt][r] + bias_v) * sc);
                }
            }
        }
    }
}

// Output projection: A = O fp16 [M][E], writes fp32 [M][E]
__global__ __launch_bounds__(256) void out_mfma(
    const _Float16* __restrict__ Oh, const _Float16* __restrict__ To,
    const float* __restrict__ bias, float* __restrict__ Out)
{
    GEMM_CORE(Oh, To)

#pragma unroll
    for (int nt = 0; nt < 4; nt++) {
        int n = n0 + wn + nt * 16 + m16;
        float bias_v = bias[n];
#pragma unroll
        for (int mt = 0; mt < 4; mt++) {
#pragma unroll
            for (int r = 0; r < 4; r++) {
                int m = m0 + wm + mt * 16 + quad * 4 + r;
                Out[(size_t)m * E_DIM + n] = acc[mt][nt][r] + bias_v;
            }
        }
    }
}

// ---------------- MFMA causal flash attention (S^T orientation) ----------------
// 128 queries/block (4 waves x 32q), 64-key chunks, double-buffered K/V.
// Computes S^T = K.Q^T (C: col=query, row=key) then O^T = V^T.P.
__global__ __launch_bounds__(256) void attn_mfma(
    const _Float16* __restrict__ Qb, const _Float16* __restrict__ Kb,
    const _Float16* __restrict__ Vb, _Float16* __restrict__ O)
{
    const int bh = blockIdx.y;
    const int qblk = (int)(gridDim.x - 1 - blockIdx.x);   // heavy blocks first
    const int q0 = qblk * 128;
    const int tid = threadIdx.x;
    const int wave = tid >> 6, lane = tid & 63;
    const int m16 = lane & 15, quad = lane >> 4;
    const int sw = m16 & 7;

    __shared__ _Float16 QP[8192];     // Q image [128][64] swizzled; reused as per-wave P
    __shared__ _Float16 Ks[2][4096];  // K chunk blobs (double buffer)
    __shared__ _Float16 Vs[2][4096];  // V^T chunk blobs

    // stage Q (16 KB linear)
    const _Float16* gQ = Qb + ((size_t)bh * 16 + qblk) * 8192;
#pragma unroll
    for (int t = 0; t < 4; t++) {
        int i = wave * 4 + t;
        GLDS16(gQ + i * 512 + lane * 8, QP + i * 512);
    }

    const _Float16* gK = Kb + (size_t)bh * 32 * 4096;
    const _Float16* gV = Vb + (size_t)bh * 32 * 4096;
    auto stage_kv = [&](int c, int buf) {
        const _Float16* ks = gK + (size_t)c * 4096;
        const _Float16* vs = gV + (size_t)c * 4096;
        int i = wave * 2;
        GLDS16(ks + i * 512 + lane * 8, &Ks[buf][i * 512]);
        GLDS16(ks + (i + 1) * 512 + lane * 8, &Ks[buf][(i + 1) * 512]);
        GLDS16(vs + i * 512 + lane * 8, &Vs[buf][i * 512]);
        GLDS16(vs + (i + 1) * 512 + lane * 8, &Vs[buf][(i + 1) * 512]);
    };
    stage_kv(0, 0);
    __syncthreads();

    // loop-invariant Q fragments (B-operand of S^T): Q[q=wave*32+mt*16+m16][d]
    half8 qf[2][2];
#pragma unroll
    for (int mt = 0; mt < 2; mt++)
#pragma unroll
        for (int dh = 0; dh < 2; dh++)
            qf[mt][dh] = *(const half8*)&QP[(wave * 32 + mt * 16 + m16) * 64
                                            + (((dh * 4 + quad) ^ sw) * 8)];

    float m_i[2] = {-INFINITY, -INFINITY}, l_i[2] = {0.f, 0.f};
    floatx4 acco[2][4];               // O^T tiles: [mt(q)][dt(d)], reg r -> d=dt*16+quad*4+r
    const floatx4 zf = {0.f, 0.f, 0.f, 0.f};
#pragma unroll
    for (int mt = 0; mt < 2; mt++)
#pragma unroll
        for (int dt = 0; dt < 4; dt++) acco[mt][dt] = zf;

    _Float16* Pw = QP + wave * 2048;  // per-wave P [32 q][64 k] swizzled (Q image dead)
    const int qmin = q0 + wave * 32;
    const int qmax = qmin + 31;
    const int nc = q0 / 64 + 2;

    for (int c = 0; c < nc; c++) {
        const int cur = c & 1;
        if (c + 1 < nc) stage_kv(c + 1, cur ^ 1);   // prefetch overlaps compute below
        const int k0 = c * 64;
        if (k0 <= qmax) {
            const _Float16* Kc = Ks[cur];
            const _Float16* Vc = Vs[cur];

            // ---- S^T = K.Q^T: 16 MFMAs (A=K frag, B=Q frag) ----
            floatx4 sf[2][4];
#pragma unroll
            for (int kt = 0; kt < 4; kt++) {
                const _Float16* kr = &Kc[(kt * 16 + m16) * 64];
                half8 kf0 = *(const half8*)&kr[((quad) ^ sw) * 8];
                half8 kf1 = *(const half8*)&kr[((4 + quad) ^ sw) * 8];
#pragma unroll
                for (int mt = 0; mt < 2; mt++)
                    sf[mt][kt] = MFMA_F16(kf1, qf[mt][1], MFMA_F16(kf0, qf[mt][0], zf));
            }

            const bool full = (k0 + 63 <= qmin);    // no masking needed
#pragma unroll
            for (int mt = 0; mt < 2; mt++) {
                const int qg = qmin + mt * 16 + m16;
                float p[4][4];
                float mx = -INFINITY;
#pragma unroll
                for (int kt = 0; kt < 4; kt++)
#pragma unroll
                    for (int r = 0; r < 4; r++) {
                        float v = sf[mt][kt][r];
                        if (!full) {
                            int key = k0 + kt * 16 + quad * 4 + r;
                            v = (key <= qg) ? v : -INFINITY;
                        }
                        p[kt][r] = v;
                        mx = fmaxf(mx, v);
                    }
                mx = fmaxf(mx, __shfl_xor(mx, 16));
                mx = fmaxf(mx, __shfl_xor(mx, 32));
                float mn = fmaxf(m_i[mt], mx);
                float alpha = __expf(m_i[mt] - mn);
                m_i[mt] = mn;
                float ls = 0.f;
#pragma unroll
                for (int kt = 0; kt < 4; kt++)
#pragma unroll
                    for (int r = 0; r < 4; r++) {
                        float e = __expf(p[kt][r] - mn);
                        p[kt][r] = e;
                        ls += e;
                    }
                ls += __shfl_xor(ls, 16);
                ls += __shfl_xor(ls, 32);
                l_i[mt] = l_i[mt] * alpha + ls;
#pragma unroll
                for (int dt = 0; dt < 4; dt++) acco[mt][dt] *= alpha;

                // P write: rows=keys are reg-contiguous -> half4 (b64) x4
#pragma unroll
                for (int kt = 0; kt < 4; kt++) {
                    half4 hv = {(_Float16)p[kt][0], (_Float16)p[kt][1],
                                (_Float16)p[kt][2], (_Float16)p[kt][3]};
                    int kb = kt * 2 + (quad >> 1);
                    *(half4*)&Pw[(mt * 16 + m16) * 64 + ((kb ^ sw) * 8) + (quad & 1) * 4] = hv;
                }
            }
            asm volatile("s_waitcnt lgkmcnt(0)" ::: "memory");   // wave-local P round trip

            // ---- O^T += V^T.P: 16 MFMAs (A=V^T frag, B=P frag) ----
            half8 pf[2][2];
#pragma unroll
            for (int mt = 0; mt < 2; mt++)
#pragma unroll
                for (int kh = 0; kh < 2; kh++)
                    pf[mt][kh] = *(const half8*)&Pw[(mt * 16 + m16) * 64
                                                    + (((kh * 4 + quad) ^ sw) * 8)];
#pragma unroll
            for (int dt = 0; dt < 4; dt++) {
                const _Float16* vr = &Vc[(dt * 16 + m16) * 64];
                half8 vf0 = *(const half8*)&vr[((quad) ^ sw) * 8];
                half8 vf1 = *(const half8*)&vr[((4 + quad) ^ sw) * 8];
#pragma unroll
                for (int mt = 0; mt < 2; mt++)
                    acco[mt][dt] = MFMA_F16(vf1, pf[mt][1],
                                    MFMA_F16(vf0, pf[mt][0], acco[mt][dt]));
            }
        }
        __syncthreads();   // all reads of buf[cur] done; drains prefetch (covered by compute)
    }

    // ---- epilogue: normalize, write O fp16 [B,S,E]; d is reg-contiguous -> half4 ----
    const int b = bh >> 4;
    const int h = bh & (H_DIM - 1);
#pragma unroll
    for (int mt = 0; mt < 2; mt++) {
        float inv = 1.f / l_i[mt];
        int q = qmin + mt * 16 + m16;
        _Float16* dst = O + (size_t)(b * S_DIM + q) * E_DIM + h * 64;
#pragma unroll
        for (int dt = 0; dt < 4; dt++) {
            half4 hv = {(_Float16)(acco[mt][dt][0] * inv), (_Float16)(acco[mt][dt][1] * inv),
                        (_Float16)(acco[mt][dt][2] * inv), (_Float16)(acco[mt][dt][3] * inv)};
            *(half4*)&dst[dt * 16 + quad * 4] = hv;
        }
    }
}

// ---------------- launch ----------------
extern "C" void kernel_launch(void* const* d_in, const int* in_sizes, int n_in,
                              void* d_out, int out_size, void* d_ws, size_t ws_size,
                              hipStream_t stream) {
    const float* x  = (const float*)d_in[0];
    const float* Wq = (const float*)d_in[1];
    const float* bq = (const float*)d_in[2];
    const float* Wk = (const float*)d_in[3];
    const float* bk = (const float*)d_in[4];
    const float* Wv = (const float*)d_in[5];
    const float* bv = (const float*)d_in[6];
    const float* Wo = (const float*)d_in[7];
    const float* bo = (const float*)d_in[8];

    const size_t SZ = (size_t)M_DIM * E_DIM;   // 8 Mi elements
    const size_t WZ = (size_t)E_DIM * E_DIM;
    _Float16* Xh = (_Float16*)d_ws;            // 16 MB (reused as Oh)
    _Float16* Tq = Xh + SZ;
    _Float16* Tk = Tq + WZ;
    _Float16* Tv = Tk + WZ;
    _Float16* To = Tv + WZ;
    _Float16* Qb = To + WZ;                    // swizzled blobs, 16 MB each
    _Float16* Kb = Qb + SZ;
    _Float16* Vb = Kb + SZ;
    _Float16* Oh = Xh;                         // alias: x dead after qkv_mfma

    cvt_x<<<dim3(M_DIM * E_DIM / 2048), 256, 0, stream>>>(x, Xh);
    cvt_w<<<dim3(16, 16, 4), 256, 0, stream>>>(Wq, Wk, Wv, Wo, Tq, Tk, Tv, To);

    qkv_mfma<<<dim3(M_DIM / 128, E_DIM / 128, 3), 256, 0, stream>>>(
        Xh, Tq, bq, Tk, bk, Tv, bv, Qb, Kb, Vb);

    attn_mfma<<<dim3(S_DIM / 128, B_DIM * H_DIM), 256, 0, stream>>>(Qb, Kb, Vb, Oh);

    out_mfma<<<dim3(M_DIM / 128, E_DIM / 128), 256, 0, stream>>>(
        Oh, To, bo, (float*)d_out);
}

// Round 6
// 323.437 us; speedup vs baseline: 10.4162x; 1.0176x over previous
//
#include <hip/hip_runtime.h>
#include <math.h>

#define E_DIM 1024
#define B_DIM 4
#define S_DIM 2048
#define H_DIM 16
#define D_HEAD 64
#define M_DIM (B_DIM * S_DIM)   // 8192
#define LOG2E 1.44269504f

typedef _Float16 half8 __attribute__((ext_vector_type(8)));
typedef _Float16 half4 __attribute__((ext_vector_type(4)));
typedef float floatx4 __attribute__((ext_vector_type(4)));
#define MFMA_F16(a, b, c) __builtin_amdgcn_mfma_f32_16x16x32_f16(a, b, c, 0, 0, 0)

// async global->LDS, 16B per lane; LDS dest = wave-uniform base + lane*16B
#define GLDS16(g, l)                                                          \
    __builtin_amdgcn_global_load_lds(                                         \
        (const __attribute__((address_space(1))) void*)(g),                   \
        (__attribute__((address_space(3))) void*)(l), 16, 0, 0)

// Split-K segment work list (40 segs per bh), sorted heavy-first.
// nseg(qb) = qb/4 + 1; seg covers chunks [8s, min(8s+8, 2qb+2)) of 64 keys.
__device__ const int SEG_QBLK[40] = {3,4,5,6,7,7,8,8,9,9,10,10,11,11,11,12,12,12,
                                     13,13,13,14,14,14,15,15,15,15,
                                     2,6,10,14, 1,5,9,13, 0,4,8,12};
__device__ const int SEG_SEG[40]  = {0,0,0,0,0,1,0,1,0,1,0,1,0,1,2,0,1,2,
                                     0,1,2,0,1,2,0,1,2,3,
                                     0,1,2,3, 0,1,2,3, 0,1,2,3};
__device__ const int SEG_BASE[16] = {0,1,2,3,4,6,8,10,12,15,18,21,24,28,32,36};

// ---------------- x: fp32 -> fp16 cast copy ----------------
__global__ __launch_bounds__(256) void cvt_x(
    const float* __restrict__ X, _Float16* __restrict__ Xh)
{
    size_t i = ((size_t)blockIdx.x * 256 + threadIdx.x) * 8;
    float4 a = *(const float4*)&X[i];
    float4 b = *(const float4*)&X[i + 4];
    half8 h = {(_Float16)a.x, (_Float16)a.y, (_Float16)a.z, (_Float16)a.w,
               (_Float16)b.x, (_Float16)b.y, (_Float16)b.z, (_Float16)b.w};
    *(half8*)&Xh[i] = h;
}

// ---------------- W: fp32 [k][n] -> fp16 [n][k] transpose ----------------
__global__ __launch_bounds__(256) void cvt_w(
    const float* __restrict__ W0, const float* __restrict__ W1,
    const float* __restrict__ W2, const float* __restrict__ W3,
    _Float16* __restrict__ T0, _Float16* __restrict__ T1,
    _Float16* __restrict__ T2, _Float16* __restrict__ T3)
{
    const int z = blockIdx.z;
    const float* W = (z == 0) ? W0 : (z == 1) ? W1 : (z == 2) ? W2 : W3;
    _Float16*   T  = (z == 0) ? T0 : (z == 1) ? T1 : (z == 2) ? T2 : T3;
    const int k0 = blockIdx.x * 64, n0 = blockIdx.y * 64;
    const int tid = threadIdx.x;
    __shared__ float t[64][65];
#pragma unroll
    for (int it = 0; it < 4; it++) {
        int r = it * 16 + (tid >> 4);
        int c = (tid & 15) * 4;
        float4 v = *(const float4*)&W[(size_t)(k0 + r) * E_DIM + n0 + c];
        t[r][c] = v.x; t[r][c + 1] = v.y; t[r][c + 2] = v.z; t[r][c + 3] = v.w;
    }
    __syncthreads();
#pragma unroll
    for (int it = 0; it < 2; it++) {
        int n = it * 32 + (tid >> 3);
        int kk = (tid & 7) * 8;
        half8 h;
#pragma unroll
        for (int j = 0; j < 8; j++) h[j] = (_Float16)t[kk + j][n];
        *(half8*)&T[(size_t)(n0 + n) * E_DIM + k0 + kk] = h;
    }
}

// ---------------- MFMA GEMM core (m97 structure) ----------------
#define GEMM_CORE(Aptr, Bptr)                                                 \
    const int tid = threadIdx.x;                                              \
    const int wave = tid >> 6, lane = tid & 63;                               \
    const int m16 = lane & 15, quad = lane >> 4;                              \
    const int wm = (wave >> 1) * 64, wn = (wave & 1) * 64;                    \
    const int m0 = blockIdx.x * 128, n0 = blockIdx.y * 128;                   \
    __shared__ _Float16 As[128 * 32];                                         \
    __shared__ _Float16 Bs[128 * 32];                                         \
    floatx4 acc[4][4];                                                        \
    const floatx4 zf = {0.f, 0.f, 0.f, 0.f};                                  \
    _Pragma("unroll") for (int i = 0; i < 4; i++)                             \
        _Pragma("unroll") for (int j = 0; j < 4; j++) acc[i][j] = zf;         \
    const int lrow = lane >> 2, lseg = lane & 3;                              \
    const _Float16* gA = (Aptr) + (size_t)(m0 + wave * 32 + lrow) * E_DIM + lseg * 8; \
    const _Float16* gB = (Bptr) + (size_t)(n0 + wave * 32 + lrow) * E_DIM + lseg * 8; \
    _Float16* lA = As + (wave * 32) * 32;                                     \
    _Float16* lB = Bs + (wave * 32) * 32;                                     \
    for (int k0 = 0; k0 < E_DIM; k0 += 32) {                                  \
        __syncthreads();                                                      \
        GLDS16(gA + k0, lA);                                                  \
        GLDS16(gA + 16 * E_DIM + k0, lA + 16 * 32);                           \
        GLDS16(gB + k0, lB);                                                  \
        GLDS16(gB + 16 * E_DIM + k0, lB + 16 * 32);                           \
        __syncthreads();                                                      \
        half8 af[4], bf[4];                                                   \
        _Pragma("unroll") for (int mt = 0; mt < 4; mt++)                      \
            af[mt] = *(const half8*)&As[(wm + mt * 16 + m16) * 32 + quad * 8];\
        _Pragma("unroll") for (int nt = 0; nt < 4; nt++)                      \
            bf[nt] = *(const half8*)&Bs[(wn + nt * 16 + m16) * 32 + quad * 8];\
        _Pragma("unroll") for (int mt = 0; mt < 4; mt++)                      \
            _Pragma("unroll") for (int nt = 0; nt < 4; nt++)                  \
                acc[mt][nt] = MFMA_F16(af[mt], bf[nt], acc[mt][nt]);          \
    }

// QKV projection epilogues write bank-swizzled blobs (16B block db ^ (row&7)):
//  Q blob: per (bh,qblk128): [q][d], pre-scaled by 0.125*log2(e) (exp2 softmax)
//  K blob: per (bh,kc64):    [k][d]
//  V blob: per (bh,kc64): V^T [d][k]
__global__ __launch_bounds__(256) void qkv_mfma(
    const _Float16* __restrict__ Xh,
    const _Float16* __restrict__ Tq, const float* __restrict__ bq,
    const _Float16* __restrict__ Tk, const float* __restrict__ bk,
    const _Float16* __restrict__ Tv, const float* __restrict__ bv,
    _Float16* __restrict__ Qo, _Float16* __restrict__ Ko, _Float16* __restrict__ Vo)
{
    const int z = blockIdx.z;
    const _Float16* Wt   = (z == 0) ? Tq : (z == 1) ? Tk : Tv;
    const float*    bias = (z == 0) ? bq : (z == 1) ? bk : bv;

    GEMM_CORE(Xh, Wt)

    if (z == 2) {
#pragma unroll
        for (int nt = 0; nt < 4; nt++) {
            int n = n0 + wn + nt * 16 + m16;
            int h = n >> 6, d = n & 63, d7 = n & 7;
            float bias_v = bias[n];
#pragma unroll
            for (int mt = 0; mt < 4; mt++) {
                int m_b = m0 + wm + mt * 16 + quad * 4;
                int b = m_b >> 11, s = m_b & 2047;
                int bh = b * H_DIM + h;
                size_t off = ((size_t)bh * 32 + (s >> 6)) * 4096
                           + (size_t)d * 64 + ((((s >> 3) & 7) ^ d7) * 8) + (s & 7);
                half4 hv;
#pragma unroll
                for (int r = 0; r < 4; r++) hv[r] = (_Float16)(acc[mt][nt][r] + bias_v);
                *(half4*)&Vo[off] = hv;
            }
        }
    } else {
        _Float16* Out = (z == 0) ? Qo : Ko;
        const float sc = (z == 0) ? 0.125f * LOG2E : 1.0f;
#pragma unroll
        for (int nt = 0; nt < 4; nt++) {
            int n = n0 + wn + nt * 16 + m16;
            int h = n >> 6;
            int db = (n >> 3) & 7, d7 = n & 7;
            float bias_v = bias[n];
#pragma unroll
            for (int mt = 0; mt < 4; mt++) {
#pragma unroll
                for (int r = 0; r < 4; r++) {
                    int m = m0 + wm + mt * 16 + quad * 4 + r;
                    int b = m >> 11, s = m & 2047;
                    int bh = b * H_DIM + h;
                    size_t off;
                    if (z == 0)
                        off = ((size_t)bh * 16 + (s >> 7)) * 8192
                            + (size_t)(s & 127) * 64 + ((db ^ (s & 7)) * 8) + d7;
                    else
                        off = ((size_t)bh * 32 + (s >> 6)) * 4096
                            + (size_t)(s & 63) * 64 + ((db ^ (s & 7)) * 8) + d7;
                    Out[off] = (_Float16)((acc[mt][nt][r] + bias_v) * sc);
                }
            }
        }
    }
}

// Output projection: A = O fp16 [M][E], writes fp32 [M][E]
__global__ __launch_bounds__(256) void out_mfma(
    const _Float16* __restrict__ Oh, const _Float16* __restrict__ To,
    const float* __restrict__ bias, float* __restrict__ Out)
{
    GEMM_CORE(Oh, To)

#pragma unroll
    for (int nt = 0; nt < 4; nt++) {
        int n = n0 + wn + nt * 16 + m16;
        float bias_v = bias[n];
#pragma unroll
        for (int mt = 0; mt < 4; mt++) {
#pragma unroll
            for (int r = 0; r < 4; r++) {
                int m = m0 + wm + mt * 16 + quad * 4 + r;
                Out[(size_t)m * E_DIM + n] = acc[mt][nt][r] + bias_v;
            }
        }
    }
}

// ---------------- Split-K MFMA causal flash attention ----------------
// Block = (work-id -> (qblk, seg), bh). Segment = up to 8 chunks of 64 keys.
// Emits unnormalized partial O~ (fp16) + per-row (m, l) in exp2 domain.
__global__ __launch_bounds__(256) void attn_mfma(
    const _Float16* __restrict__ Qb, const _Float16* __restrict__ Kb,
    const _Float16* __restrict__ Vb, _Float16* __restrict__ Opart,
    float* __restrict__ Mv, float* __restrict__ Lv)
{
    const int bh = blockIdx.y;
    const int wid = blockIdx.x;
    const int qblk = SEG_QBLK[wid];
    const int seg  = SEG_SEG[wid];
    const int q0 = qblk * 128;
    const int c0 = seg * 8;
    const int c1 = min(c0 + 8, 2 * qblk + 2);
    const int tid = threadIdx.x;
    const int wave = tid >> 6, lane = tid & 63;
    const int m16 = lane & 15, quad = lane >> 4;
    const int sw = m16 & 7;

    __shared__ _Float16 QP[8192];     // Q image [128][64] swizzled; reused as per-wave P
    __shared__ _Float16 Ks[2][4096];  // K chunk blobs (double buffer)
    __shared__ _Float16 Vs[2][4096];  // V^T chunk blobs

    // stage Q (16 KB linear)
    const _Float16* gQ = Qb + ((size_t)bh * 16 + qblk) * 8192;
#pragma unroll
    for (int t = 0; t < 4; t++) {
        int i = wave * 4 + t;
        GLDS16(gQ + i * 512 + lane * 8, QP + i * 512);
    }

    const _Float16* gK = Kb + (size_t)bh * 32 * 4096;
    const _Float16* gV = Vb + (size_t)bh * 32 * 4096;
    auto stage_kv = [&](int c, int buf) {
        const _Float16* ks = gK + (size_t)c * 4096;
        const _Float16* vs = gV + (size_t)c * 4096;
        int i = wave * 2;
        GLDS16(ks + i * 512 + lane * 8, &Ks[buf][i * 512]);
        GLDS16(ks + (i + 1) * 512 + lane * 8, &Ks[buf][(i + 1) * 512]);
        GLDS16(vs + i * 512 + lane * 8, &Vs[buf][i * 512]);
        GLDS16(vs + (i + 1) * 512 + lane * 8, &Vs[buf][(i + 1) * 512]);
    };
    stage_kv(c0, c0 & 1);
    __syncthreads();

    // loop-invariant Q fragments (B-operand of S^T)
    half8 qf[2][2];
#pragma unroll
    for (int mt = 0; mt < 2; mt++)
#pragma unroll
        for (int dh = 0; dh < 2; dh++)
            qf[mt][dh] = *(const half8*)&QP[(wave * 32 + mt * 16 + m16) * 64
                                            + (((dh * 4 + quad) ^ sw) * 8)];

    float m_i[2] = {-INFINITY, -INFINITY}, l_i[2] = {0.f, 0.f};
    floatx4 acco[2][4];
    const floatx4 zf = {0.f, 0.f, 0.f, 0.f};
#pragma unroll
    for (int mt = 0; mt < 2; mt++)
#pragma unroll
        for (int dt = 0; dt < 4; dt++) acco[mt][dt] = zf;

    _Float16* Pw = QP + wave * 2048;
    const int qmin = q0 + wave * 32;
    const int qmax = qmin + 31;

    for (int c = c0; c < c1; c++) {
        const int cur = c & 1;
        if (c + 1 < c1) stage_kv(c + 1, cur ^ 1);   // prefetch overlaps compute
        const int k0 = c * 64;
        if (k0 <= qmax) {
            const _Float16* Kc = Ks[cur];
            const _Float16* Vc = Vs[cur];

            // ---- S^T = K.Q^T: 16 MFMAs ----
            floatx4 sf[2][4];
#pragma unroll
            for (int kt = 0; kt < 4; kt++) {
                const _Float16* kr = &Kc[(kt * 16 + m16) * 64];
                half8 kf0 = *(const half8*)&kr[((quad) ^ sw) * 8];
                half8 kf1 = *(const half8*)&kr[((4 + quad) ^ sw) * 8];
#pragma unroll
                for (int mt = 0; mt < 2; mt++)
                    sf[mt][kt] = MFMA_F16(kf1, qf[mt][1], MFMA_F16(kf0, qf[mt][0], zf));
            }

            const bool full = (k0 + 63 <= qmin);
#pragma unroll
            for (int mt = 0; mt < 2; mt++) {
                const int qg = qmin + mt * 16 + m16;
                float p[4][4];
                float mx = -INFINITY;
#pragma unroll
                for (int kt = 0; kt < 4; kt++)
#pragma unroll
                    for (int r = 0; r < 4; r++) {
                        float v = sf[mt][kt][r];
                        if (!full) {
                            int key = k0 + kt * 16 + quad * 4 + r;
                            v = (key <= qg) ? v : -INFINITY;
                        }
                        p[kt][r] = v;
                        mx = fmaxf(mx, v);
                    }
                mx = fmaxf(mx, __shfl_xor(mx, 16));
                mx = fmaxf(mx, __shfl_xor(mx, 32));
                float mn = fmaxf(m_i[mt], mx);
                float alpha = exp2f(m_i[mt] - mn);
                m_i[mt] = mn;
                float ls = 0.f;
#pragma unroll
                for (int kt = 0; kt < 4; kt++)
#pragma unroll
                    for (int r = 0; r < 4; r++) {
                        float e = exp2f(p[kt][r] - mn);
                        p[kt][r] = e;
                        ls += e;
                    }
                ls += __shfl_xor(ls, 16);
                ls += __shfl_xor(ls, 32);
                l_i[mt] = l_i[mt] * alpha + ls;
#pragma unroll
                for (int dt = 0; dt < 4; dt++) acco[mt][dt] *= alpha;

#pragma unroll
                for (int kt = 0; kt < 4; kt++) {
                    half4 hv = {(_Float16)p[kt][0], (_Float16)p[kt][1],
                                (_Float16)p[kt][2], (_Float16)p[kt][3]};
                    int kb = kt * 2 + (quad >> 1);
                    *(half4*)&Pw[(mt * 16 + m16) * 64 + ((kb ^ sw) * 8) + (quad & 1) * 4] = hv;
                }
            }
            asm volatile("s_waitcnt lgkmcnt(0)" ::: "memory");

            // ---- O^T += V^T.P: 16 MFMAs ----
            half8 pf[2][2];
#pragma unroll
            for (int mt = 0; mt < 2; mt++)
#pragma unroll
                for (int kh = 0; kh < 2; kh++)
                    pf[mt][kh] = *(const half8*)&Pw[(mt * 16 + m16) * 64
                                                    + (((kh * 4 + quad) ^ sw) * 8)];
#pragma unroll
            for (int dt = 0; dt < 4; dt++) {
                const _Float16* vr = &Vc[(dt * 16 + m16) * 64];
                half8 vf0 = *(const half8*)&vr[((quad) ^ sw) * 8];
                half8 vf1 = *(const half8*)&vr[((4 + quad) ^ sw) * 8];
#pragma unroll
                for (int mt = 0; mt < 2; mt++)
                    acco[mt][dt] = MFMA_F16(vf1, pf[mt][1],
                                    MFMA_F16(vf0, pf[mt][0], acco[mt][dt]));
            }
        }
        __syncthreads();
    }

    // ---- epilogue: write unnormalized partial + (m,l) ----
    const size_t prow = ((size_t)bh * 40 + SEG_BASE[qblk] + seg) * 128;
#pragma unroll
    for (int mt = 0; mt < 2; mt++) {
        int lq = wave * 32 + mt * 16 + m16;
        if (quad == 0) {
            Mv[prow + lq] = m_i[mt];
            Lv[prow + lq] = l_i[mt];
        }
        _Float16* dst = Opart + (prow + lq) * 64;
#pragma unroll
        for (int dt = 0; dt < 4; dt++) {
            half4 hv = {(_Float16)acco[mt][dt][0], (_Float16)acco[mt][dt][1],
                        (_Float16)acco[mt][dt][2], (_Float16)acco[mt][dt][3]};
            *(half4*)&dst[dt * 16 + quad * 4] = hv;
        }
    }
}

// ---------------- combine partials -> O fp16 [B,S,E] ----------------
__global__ __launch_bounds__(256) void attn_combine(
    const _Float16* __restrict__ Opart, const float* __restrict__ Mv,
    const float* __restrict__ Lv, _Float16* __restrict__ O)
{
    const int qb = blockIdx.x, bh = blockIdx.y;
    const int nseg = (qb >> 2) + 1;
    const size_t pbase = ((size_t)bh * 40 + SEG_BASE[qb]) * 128;
    const int t = threadIdx.x;
    const int r = t >> 1, dh = (t & 1) * 32;

    float m_s[4], w[4];
    float M = -INFINITY;
    for (int s = 0; s < nseg; s++) {
        m_s[s] = Mv[pbase + s * 128 + r];
        M = fmaxf(M, m_s[s]);
    }
    float L = 0.f;
    for (int s = 0; s < nseg; s++) {
        w[s] = exp2f(m_s[s] - M);
        L += Lv[pbase + s * 128 + r] * w[s];
    }
    const float invL = 1.f / L;

    const int b = bh >> 4, h = bh & (H_DIM - 1);
    const int q = qb * 128 + r;
    _Float16* dst = O + (size_t)(b * S_DIM + q) * E_DIM + h * 64 + dh;
#pragma unroll
    for (int d0 = 0; d0 < 32; d0 += 8) {
        float acc[8] = {0.f, 0.f, 0.f, 0.f, 0.f, 0.f, 0.f, 0.f};
        for (int s = 0; s < nseg; s++) {
            half8 v = *(const half8*)&Opart[(pbase + s * 128 + r) * 64 + dh + d0];
#pragma unroll
            for (int j = 0; j < 8; j++) acc[j] += w[s] * (float)v[j];
        }
        half8 o;
#pragma unroll
        for (int j = 0; j < 8; j++) o[j] = (_Float16)(acc[j] * invL);
        *(half8*)&dst[d0] = o;
    }
}

// ---------------- launch ----------------
extern "C" void kernel_launch(void* const* d_in, const int* in_sizes, int n_in,
                              void* d_out, int out_size, void* d_ws, size_t ws_size,
                              hipStream_t stream) {
    const float* x  = (const float*)d_in[0];
    const float* Wq = (const float*)d_in[1];
    const float* bq = (const float*)d_in[2];
    const float* Wk = (const float*)d_in[3];
    const float* bk = (const float*)d_in[4];
    const float* Wv = (const float*)d_in[5];
    const float* bv = (const float*)d_in[6];
    const float* Wo = (const float*)d_in[7];
    const float* bo = (const float*)d_in[8];

    const size_t SZ = (size_t)M_DIM * E_DIM;   // 8 Mi elements
    const size_t WZ = (size_t)E_DIM * E_DIM;
    _Float16* Xh = (_Float16*)d_ws;            // 16 MB (reused as Oh)
    _Float16* Tq = Xh + SZ;
    _Float16* Tk = Tq + WZ;
    _Float16* Tv = Tk + WZ;
    _Float16* To = Tv + WZ;
    _Float16* Qb = To + WZ;                    // swizzled blobs, 16 MB each
    _Float16* Kb = Qb + SZ;
    _Float16* Vb = Kb + SZ;
    _Float16* Opart = Vb + SZ;                 // 2560 * 8192 fp16 = 41.9 MB
    float* Mv = (float*)(Opart + (size_t)2560 * 8192);   // 2560*128 fp32
    float* Lv = Mv + 2560 * 128;
    _Float16* Oh = Xh;                         // alias: x dead after qkv_mfma

    cvt_x<<<dim3(M_DIM * E_DIM / 2048), 256, 0, stream>>>(x, Xh);
    cvt_w<<<dim3(16, 16, 4), 256, 0, stream>>>(Wq, Wk, Wv, Wo, Tq, Tk, Tv, To);

    qkv_mfma<<<dim3(M_DIM / 128, E_DIM / 128, 3), 256, 0, stream>>>(
        Xh, Tq, bq, Tk, bk, Tv, bv, Qb, Kb, Vb);

    attn_mfma<<<dim3(40, B_DIM * H_DIM), 256, 0, stream>>>(
        Qb, Kb, Vb, Opart, Mv, Lv);

    attn_combine<<<dim3(16, B_DIM * H_DIM), 256, 0, stream>>>(Opart, Mv, Lv, Oh);

    out_mfma<<<dim3(M_DIM / 128, E_DIM / 128), 256, 0, stream>>>(
        Oh, To, bo, (float*)d_out);
}

// Round 8
// 299.048 us; speedup vs baseline: 11.2656x; 1.0816x over previous
//
#include <hip/hip_runtime.h>
#include <math.h>

#define E_DIM 1024
#define B_DIM 4
#define S_DIM 2048
#define H_DIM 16
#define D_HEAD 64
#define M_DIM (B_DIM * S_DIM)   // 8192
#define LOG2E 1.44269504f

typedef _Float16 half8 __attribute__((ext_vector_type(8)));
typedef _Float16 half4 __attribute__((ext_vector_type(4)));
typedef __fp16  fp16x2 __attribute__((ext_vector_type(2)));   // cvt_pkrtz return type
typedef float floatx4 __attribute__((ext_vector_type(4)));
#define MFMA_F16(a, b, c) __builtin_amdgcn_mfma_f32_16x16x32_f16(a, b, c, 0, 0, 0)

#if __has_builtin(__builtin_amdgcn_exp2f)
#define EXP2F(x) __builtin_amdgcn_exp2f(x)
#else
#define EXP2F(x) exp2f(x)
#endif

union H4 { fp16x2 h2[2]; half4 h4; };

// async global->LDS, 16B per lane; LDS dest = wave-uniform base + lane*16B
#define GLDS16(g, l)                                                          \
    __builtin_amdgcn_global_load_lds(                                         \
        (const __attribute__((address_space(1))) void*)(g),                   \
        (__attribute__((address_space(3))) void*)(l), 16, 0, 0)

// Split-K segment work list (40 segs per bh), sorted heavy-first.
// nseg(qb) = qb/4 + 1; seg covers chunks [8s, min(8s+8, 2qb+2)) of 64 keys.
__device__ const int SEG_QBLK[40] = {3,4,5,6,7,7,8,8,9,9,10,10,11,11,11,12,12,12,
                                     13,13,13,14,14,14,15,15,15,15,
                                     2,6,10,14, 1,5,9,13, 0,4,8,12};
__device__ const int SEG_SEG[40]  = {0,0,0,0,0,1,0,1,0,1,0,1,0,1,2,0,1,2,
                                     0,1,2,0,1,2,0,1,2,3,
                                     0,1,2,3, 0,1,2,3, 0,1,2,3};
__device__ const int SEG_BASE[16] = {0,1,2,3,4,6,8,10,12,15,18,21,24,28,32,36};

// ---------------- x: fp32 -> fp16 cast copy ----------------
__global__ __launch_bounds__(256) void cvt_x(
    const float* __restrict__ X, _Float16* __restrict__ Xh)
{
    size_t i = ((size_t)blockIdx.x * 256 + threadIdx.x) * 8;
    float4 a = *(const float4*)&X[i];
    float4 b = *(const float4*)&X[i + 4];
    half8 h = {(_Float16)a.x, (_Float16)a.y, (_Float16)a.z, (_Float16)a.w,
               (_Float16)b.x, (_Float16)b.y, (_Float16)b.z, (_Float16)b.w};
    *(half8*)&Xh[i] = h;
}

// ---------------- W: fp32 [k][n] -> fp16 [n][k] transpose ----------------
__global__ __launch_bounds__(256) void cvt_w(
    const float* __restrict__ W0, const float* __restrict__ W1,
    const float* __restrict__ W2, const float* __restrict__ W3,
    _Float16* __restrict__ T0, _Float16* __restrict__ T1,
    _Float16* __restrict__ T2, _Float16* __restrict__ T3)
{
    const int z = blockIdx.z;
    const float* W = (z == 0) ? W0 : (z == 1) ? W1 : (z == 2) ? W2 : W3;
    _Float16*   T  = (z == 0) ? T0 : (z == 1) ? T1 : (z == 2) ? T2 : T3;
    const int k0 = blockIdx.x * 64, n0 = blockIdx.y * 64;
    const int tid = threadIdx.x;
    __shared__ float t[64][65];
#pragma unroll
    for (int it = 0; it < 4; it++) {
        int r = it * 16 + (tid >> 4);
        int c = (tid & 15) * 4;
        float4 v = *(const float4*)&W[(size_t)(k0 + r) * E_DIM + n0 + c];
        t[r][c] = v.x; t[r][c + 1] = v.y; t[r][c + 2] = v.z; t[r][c + 3] = v.w;
    }
    __syncthreads();
#pragma unroll
    for (int it = 0; it < 2; it++) {
        int n = it * 32 + (tid >> 3);
        int kk = (tid & 7) * 8;
        half8 h;
#pragma unroll
        for (int j = 0; j < 8; j++) h[j] = (_Float16)t[kk + j][n];
        *(half8*)&T[(size_t)(n0 + n) * E_DIM + k0 + kk] = h;
    }
}

// ---------------- MFMA GEMM core (m97 structure) ----------------
#define GEMM_CORE(Aptr, Bptr)                                                 \
    const int tid = threadIdx.x;                                              \
    const int wave = tid >> 6, lane = tid & 63;                               \
    const int m16 = lane & 15, quad = lane >> 4;                              \
    const int wm = (wave >> 1) * 64, wn = (wave & 1) * 64;                    \
    const int m0 = blockIdx.x * 128, n0 = blockIdx.y * 128;                   \
    __shared__ _Float16 As[128 * 32];                                         \
    __shared__ _Float16 Bs[128 * 32];                                         \
    floatx4 acc[4][4];                                                        \
    const floatx4 zf = {0.f, 0.f, 0.f, 0.f};                                  \
    _Pragma("unroll") for (int i = 0; i < 4; i++)                             \
        _Pragma("unroll") for (int j = 0; j < 4; j++) acc[i][j] = zf;         \
    const int lrow = lane >> 2, lseg = lane & 3;                              \
    const _Float16* gA = (Aptr) + (size_t)(m0 + wave * 32 + lrow) * E_DIM + lseg * 8; \
    const _Float16* gB = (Bptr) + (size_t)(n0 + wave * 32 + lrow) * E_DIM + lseg * 8; \
    _Float16* lA = As + (wave * 32) * 32;                                     \
    _Float16* lB = Bs + (wave * 32) * 32;                                     \
    for (int k0 = 0; k0 < E_DIM; k0 += 32) {                                  \
        __syncthreads();                                                      \
        GLDS16(gA + k0, lA);                                                  \
        GLDS16(gA + 16 * E_DIM + k0, lA + 16 * 32);                           \
        GLDS16(gB + k0, lB);                                                  \
        GLDS16(gB + 16 * E_DIM + k0, lB + 16 * 32);                           \
        __syncthreads();                                                      \
        half8 af[4], bf[4];                                                   \
        _Pragma("unroll") for (int mt = 0; mt < 4; mt++)                      \
            af[mt] = *(const half8*)&As[(wm + mt * 16 + m16) * 32 + quad * 8];\
        _Pragma("unroll") for (int nt = 0; nt < 4; nt++)                      \
            bf[nt] = *(const half8*)&Bs[(wn + nt * 16 + m16) * 32 + quad * 8];\
        _Pragma("unroll") for (int mt = 0; mt < 4; mt++)                      \
            _Pragma("unroll") for (int nt = 0; nt < 4; nt++)                  \
                acc[mt][nt] = MFMA_F16(af[mt], bf[nt], acc[mt][nt]);          \
    }

// QKV projection epilogues write bank-swizzled blobs (16B block db ^ (row&7)):
//  Q blob: per (bh,qblk128): [q][d], pre-scaled by 0.125*log2(e) (exp2 softmax)
//  K blob: per (bh,kc64):    [k][d]
//  V blob: per (bh,kc64): V^T [d][k]
__global__ __launch_bounds__(256) void qkv_mfma(
    const _Float16* __restrict__ Xh,
    const _Float16* __restrict__ Tq, const float* __restrict__ bq,
    const _Float16* __restrict__ Tk, const float* __restrict__ bk,
    const _Float16* __restrict__ Tv, const float* __restrict__ bv,
    _Float16* __restrict__ Qo, _Float16* __restrict__ Ko, _Float16* __restrict__ Vo)
{
    const int z = blockIdx.z;
    const _Float16* Wt   = (z == 0) ? Tq : (z == 1) ? Tk : Tv;
    const float*    bias = (z == 0) ? bq : (z == 1) ? bk : bv;

    GEMM_CORE(Xh, Wt)

    if (z == 2) {
#pragma unroll
        for (int nt = 0; nt < 4; nt++) {
            int n = n0 + wn + nt * 16 + m16;
            int h = n >> 6, d = n & 63, d7 = n & 7;
            float bias_v = bias[n];
#pragma unroll
            for (int mt = 0; mt < 4; mt++) {
                int m_b = m0 + wm + mt * 16 + quad * 4;
                int b = m_b >> 11, s = m_b & 2047;
                int bh = b * H_DIM + h;
                size_t off = ((size_t)bh * 32 + (s >> 6)) * 4096
                           + (size_t)d * 64 + ((((s >> 3) & 7) ^ d7) * 8) + (s & 7);
                half4 hv;
#pragma unroll
                for (int r = 0; r < 4; r++) hv[r] = (_Float16)(acc[mt][nt][r] + bias_v);
                *(half4*)&Vo[off] = hv;
            }
        }
    } else {
        _Float16* Out = (z == 0) ? Qo : Ko;
        const float sc = (z == 0) ? 0.125f * LOG2E : 1.0f;
#pragma unroll
        for (int nt = 0; nt < 4; nt++) {
            int n = n0 + wn + nt * 16 + m16;
            int h = n >> 6;
            int db = (n >> 3) & 7, d7 = n & 7;
            float bias_v = bias[n];
#pragma unroll
            for (int mt = 0; mt < 4; mt++) {
#pragma unroll
                for (int r = 0; r < 4; r++) {
                    int m = m0 + wm + mt * 16 + quad * 4 + r;
                    int b = m >> 11, s = m & 2047;
                    int bh = b * H_DIM + h;
                    size_t off;
                    if (z == 0)
                        off = ((size_t)bh * 16 + (s >> 7)) * 8192
                            + (size_t)(s & 127) * 64 + ((db ^ (s & 7)) * 8) + d7;
                    else
                        off = ((size_t)bh * 32 + (s >> 6)) * 4096
                            + (size_t)(s & 63) * 64 + ((db ^ (s & 7)) * 8) + d7;
                    Out[off] = (_Float16)((acc[mt][nt][r] + bias_v) * sc);
                }
            }
        }
    }
}

// Output projection: A = O fp16 [M][E], writes fp32 [M][E]
__global__ __launch_bounds__(256) void out_mfma(
    const _Float16* __restrict__ Oh, const _Float16* __restrict__ To,
    const float* __restrict__ bias, float* __restrict__ Out)
{
    GEMM_CORE(Oh, To)

#pragma unroll
    for (int nt = 0; nt < 4; nt++) {
        int n = n0 + wn + nt * 16 + m16;
        float bias_v = bias[n];
#pragma unroll
        for (int mt = 0; mt < 4; mt++) {
#pragma unroll
            for (int r = 0; r < 4; r++) {
                int m = m0 + wm + mt * 16 + quad * 4 + r;
                Out[(size_t)m * E_DIM + n] = acc[mt][nt][r] + bias_v;
            }
        }
    }
}

// ---------------- Split-K MFMA causal flash attention ----------------
// Solo segments (qb 0-3 cover all their keys) write O directly; others emit
// unnormalized partial O~ (fp16) + per-row (m, l) in exp2 domain.
__global__ __launch_bounds__(256) void attn_mfma(
    const _Float16* __restrict__ Qb, const _Float16* __restrict__ Kb,
    const _Float16* __restrict__ Vb, _Float16* __restrict__ Opart,
    float* __restrict__ Mv, float* __restrict__ Lv, _Float16* __restrict__ O)
{
    const int bh = blockIdx.y;
    const int wid = blockIdx.x;
    const int qblk = SEG_QBLK[wid];
    const int seg  = SEG_SEG[wid];
    const int q0 = qblk * 128;
    const int c0 = seg * 8;
    const int c1 = min(c0 + 8, 2 * qblk + 2);
    const bool solo = (c0 == 0) && (c1 == 2 * qblk + 2);
    const int tid = threadIdx.x;
    const int wave = tid >> 6, lane = tid & 63;
    const int m16 = lane & 15, quad = lane >> 4;
    const int sw = m16 & 7;

    __shared__ _Float16 QP[8192];    // Q image [128][64] swizzled; reused as per-wave P
    __shared__ _Float16 KsA[8192];   // K chunk blobs (double buffer, flat)
    __shared__ _Float16 VsA[8192];   // V^T chunk blobs

    // stage Q (16 KB linear)
    const _Float16* gQ = Qb + ((size_t)bh * 16 + qblk) * 8192;
#pragma unroll
    for (int t = 0; t < 4; t++) {
        int i = wave * 4 + t;
        GLDS16(gQ + i * 512 + lane * 8, QP + i * 512);
    }

    // persistent staging pointers (advance by 4096/chunk; no re-derivation)
    const _Float16* kp = Kb + (size_t)bh * 131072 + (size_t)c0 * 4096 + wave * 1024 + lane * 8;
    const _Float16* vp = Vb + (size_t)bh * 131072 + (size_t)c0 * 4096 + wave * 1024 + lane * 8;
    _Float16* dK = KsA + wave * 1024;
    _Float16* dV = VsA + wave * 1024;
    {
        int b0 = (c0 & 1) * 4096;
        GLDS16(kp, dK + b0);  GLDS16(kp + 512, dK + b0 + 512);
        GLDS16(vp, dV + b0);  GLDS16(vp + 512, dV + b0 + 512);
    }
    __syncthreads();

    // loop-invariant Q fragments (B-operand of S^T)
    half8 qf[2][2];
#pragma unroll
    for (int mt = 0; mt < 2; mt++)
#pragma unroll
        for (int dh = 0; dh < 2; dh++)
            qf[mt][dh] = *(const half8*)&QP[(wave * 32 + mt * 16 + m16) * 64
                                            + (((dh * 4 + quad) ^ sw) * 8)];

    // loop-invariant LDS offsets (element units)
    int ko[4][2], vo[4][2];
#pragma unroll
    for (int kt = 0; kt < 4; kt++) {
        ko[kt][0] = (kt * 16 + m16) * 64 + ((quad ^ sw) << 3);
        ko[kt][1] = (kt * 16 + m16) * 64 + (((quad + 4) ^ sw) << 3);
        vo[kt][0] = ko[kt][0];
        vo[kt][1] = ko[kt][1];
    }
    _Float16* Pw = QP + wave * 2048;
    _Float16* pwp[2][4];
    const _Float16* pfp[2][2];
#pragma unroll
    for (int mt = 0; mt < 2; mt++) {
#pragma unroll
        for (int kt = 0; kt < 4; kt++) {
            int kb = kt * 2 + (quad >> 1);
            pwp[mt][kt] = &Pw[(mt * 16 + m16) * 64 + ((kb ^ sw) << 3) + ((quad & 1) << 2)];
        }
#pragma unroll
        for (int kh = 0; kh < 2; kh++)
            pfp[mt][kh] = &Pw[(mt * 16 + m16) * 64 + (((kh * 4 + quad) ^ sw) << 3)];
    }

    float m_i[2] = {-INFINITY, -INFINITY}, l_i[2] = {0.f, 0.f};
    floatx4 acco[2][4];
    const floatx4 zf = {0.f, 0.f, 0.f, 0.f};
#pragma unroll
    for (int mt = 0; mt < 2; mt++)
#pragma unroll
        for (int dt = 0; dt < 4; dt++) acco[mt][dt] = zf;

    const int qmin = q0 + wave * 32;
    const int qmax = qmin + 31;

    for (int c = c0; c < c1; c++) {
        const int boff = (c & 1) * 4096;
        if (c + 1 < c1) {   // prefetch next chunk into other buffer
            kp += 4096; vp += 4096;
            int b1 = boff ^ 4096;
            GLDS16(kp, dK + b1);  GLDS16(kp + 512, dK + b1 + 512);
            GLDS16(vp, dV + b1);  GLDS16(vp + 512, dV + b1 + 512);
        }
        const int k0 = c * 64;
        if (k0 <= qmax) {
            // ---- S^T = K.Q^T: 16 MFMAs ----
            floatx4 sf[2][4];
#pragma unroll
            for (int kt = 0; kt < 4; kt++) {
                half8 kf0 = *(const half8*)&KsA[boff + ko[kt][0]];
                half8 kf1 = *(const half8*)&KsA[boff + ko[kt][1]];
#pragma unroll
                for (int mt = 0; mt < 2; mt++)
                    sf[mt][kt] = MFMA_F16(kf1, qf[mt][1], MFMA_F16(kf0, qf[mt][0], zf));
            }

            const bool full = (k0 + 63 <= qmin);
#pragma unroll
            for (int mt = 0; mt < 2; mt++) {
                const int qg = qmin + mt * 16 + m16;
                float p[4][4];
                float mx = -INFINITY;
#pragma unroll
                for (int kt = 0; kt < 4; kt++)
#pragma unroll
                    for (int r = 0; r < 4; r++) {
                        float v = sf[mt][kt][r];
                        if (!full) {
                            int key = k0 + kt * 16 + quad * 4 + r;
                            v = (key <= qg) ? v : -INFINITY;
                        }
                        p[kt][r] = v;
                        mx = fmaxf(mx, v);
                    }
                mx = fmaxf(mx, __shfl_xor(mx, 16));
                mx = fmaxf(mx, __shfl_xor(mx, 32));
                float mn = fmaxf(m_i[mt], mx);
                float alpha = EXP2F(m_i[mt] - mn);
                m_i[mt] = mn;
                float ls = 0.f;
#pragma unroll
                for (int kt = 0; kt < 4; kt++)
#pragma unroll
                    for (int r = 0; r < 4; r++) {
                        float e = EXP2F(p[kt][r] - mn);
                        p[kt][r] = e;
                        ls += e;
                    }
                ls += __shfl_xor(ls, 16);
                ls += __shfl_xor(ls, 32);
                l_i[mt] = l_i[mt] * alpha + ls;
#pragma unroll
                for (int dt = 0; dt < 4; dt++) acco[mt][dt] *= alpha;

                // P write: packed cvt, b64 store to precomputed pointer
#pragma unroll
                for (int kt = 0; kt < 4; kt++) {
                    H4 u;
                    u.h2[0] = __builtin_amdgcn_cvt_pkrtz(p[kt][0], p[kt][1]);
                    u.h2[1] = __builtin_amdgcn_cvt_pkrtz(p[kt][2], p[kt][3]);
                    *(half4*)pwp[mt][kt] = u.h4;
                }
            }
            asm volatile("s_waitcnt lgkmcnt(0)" ::: "memory");

            // ---- O^T += V^T.P: 16 MFMAs ----
            half8 pf[2][2];
#pragma unroll
            for (int mt = 0; mt < 2; mt++)
#pragma unroll
                for (int kh = 0; kh < 2; kh++)
                    pf[mt][kh] = *(const half8*)pfp[mt][kh];
#pragma unroll
            for (int dt = 0; dt < 4; dt++) {
                half8 vf0 = *(const half8*)&VsA[boff + vo[dt][0]];
                half8 vf1 = *(const half8*)&VsA[boff + vo[dt][1]];
#pragma unroll
                for (int mt = 0; mt < 2; mt++)
                    acco[mt][dt] = MFMA_F16(vf1, pf[mt][1],
                                    MFMA_F16(vf0, pf[mt][0], acco[mt][dt]));
            }
        }
        __syncthreads();
    }

    if (solo) {
        // ---- single segment: normalize and write O fp16 [B,S,E] directly ----
        const int b = bh >> 4;
        const int h = bh & (H_DIM - 1);
#pragma unroll
        for (int mt = 0; mt < 2; mt++) {
            float inv = 1.f / l_i[mt];
            int q = qmin + mt * 16 + m16;
            _Float16* dst = O + (size_t)(b * S_DIM + q) * E_DIM + h * 64;
#pragma unroll
            for (int dt = 0; dt < 4; dt++) {
                H4 u;
                u.h2[0] = __builtin_amdgcn_cvt_pkrtz(acco[mt][dt][0] * inv, acco[mt][dt][1] * inv);
                u.h2[1] = __builtin_amdgcn_cvt_pkrtz(acco[mt][dt][2] * inv, acco[mt][dt][3] * inv);
                *(half4*)&dst[dt * 16 + quad * 4] = u.h4;
            }
        }
    } else {
        // ---- write unnormalized partial + (m,l) ----
        const size_t prow = ((size_t)bh * 40 + SEG_BASE[qblk] + seg) * 128;
#pragma unroll
        for (int mt = 0; mt < 2; mt++) {
            int lq = wave * 32 + mt * 16 + m16;
            if (quad == 0) {
                Mv[prow + lq] = m_i[mt];
                Lv[prow + lq] = l_i[mt];
            }
            _Float16* dst = Opart + (prow + lq) * 64;
#pragma unroll
            for (int dt = 0; dt < 4; dt++) {
                H4 u;
                u.h2[0] = __builtin_amdgcn_cvt_pkrtz(acco[mt][dt][0], acco[mt][dt][1]);
                u.h2[1] = __builtin_amdgcn_cvt_pkrtz(acco[mt][dt][2], acco[mt][dt][3]);
                *(half4*)&dst[dt * 16 + quad * 4] = u.h4;
            }
        }
    }
}

// ---------------- combine partials -> O fp16 [B,S,E] (qb >= 4 only) ----------------
__global__ __launch_bounds__(256) void attn_combine(
    const _Float16* __restrict__ Opart, const float* __restrict__ Mv,
    const float* __restrict__ Lv, _Float16* __restrict__ O)
{
    const int qb = blockIdx.x + 4, bh = blockIdx.y;
    const int nseg = (qb >> 2) + 1;
    const size_t pbase = ((size_t)bh * 40 + SEG_BASE[qb]) * 128;
    const int t = threadIdx.x;
    const int r = t >> 1, dh = (t & 1) * 32;

    float m_s[4], w[4];
    float M = -INFINITY;
    for (int s = 0; s < nseg; s++) {
        m_s[s] = Mv[pbase + s * 128 + r];
        M = fmaxf(M, m_s[s]);
    }
    float L = 0.f;
    for (int s = 0; s < nseg; s++) {
        w[s] = EXP2F(m_s[s] - M);
        L += Lv[pbase + s * 128 + r] * w[s];
    }
    const float invL = 1.f / L;

    const int b = bh >> 4, h = bh & (H_DIM - 1);
    const int q = qb * 128 + r;
    _Float16* dst = O + (size_t)(b * S_DIM + q) * E_DIM + h * 64 + dh;
#pragma unroll
    for (int d0 = 0; d0 < 32; d0 += 8) {
        float acc[8] = {0.f, 0.f, 0.f, 0.f, 0.f, 0.f, 0.f, 0.f};
        for (int s = 0; s < nseg; s++) {
            half8 v = *(const half8*)&Opart[(pbase + s * 128 + r) * 64 + dh + d0];
#pragma unroll
            for (int j = 0; j < 8; j++) acc[j] += w[s] * (float)v[j];
        }
        half8 o;
#pragma unroll
        for (int j = 0; j < 8; j++) o[j] = (_Float16)(acc[j] * invL);
        *(half8*)&dst[d0] = o;
    }
}

// ---------------- launch ----------------
extern "C" void kernel_launch(void* const* d_in, const int* in_sizes, int n_in,
                              void* d_out, int out_size, void* d_ws, size_t ws_size,
                              hipStream_t stream) {
    const float* x  = (const float*)d_in[0];
    const float* Wq = (const float*)d_in[1];
    const float* bq = (const float*)d_in[2];
    const float* Wk = (const float*)d_in[3];
    const float* bk = (const float*)d_in[4];
    const float* Wv = (const float*)d_in[5];
    const float* bv = (const float*)d_in[6];
    const float* Wo = (const float*)d_in[7];
    const float* bo = (const float*)d_in[8];

    const size_t SZ = (size_t)M_DIM * E_DIM;   // 8 Mi elements
    const size_t WZ = (size_t)E_DIM * E_DIM;
    _Float16* Xh = (_Float16*)d_ws;            // 16 MB (reused as Oh)
    _Float16* Tq = Xh + SZ;
    _Float16* Tk = Tq + WZ;
    _Float16* Tv = Tk + WZ;
    _Float16* To = Tv + WZ;
    _Float16* Qb = To + WZ;                    // swizzled blobs, 16 MB each
    _Float16* Kb = Qb + SZ;
    _Float16* Vb = Kb + SZ;
    _Float16* Opart = Vb + SZ;                 // 2560 * 8192 fp16 = 41.9 MB
    float* Mv = (float*)(Opart + (size_t)2560 * 8192);   // 2560*128 fp32
    float* Lv = Mv + 2560 * 128;
    _Float16* Oh = Xh;                         // alias: x dead after qkv_mfma

    cvt_x<<<dim3(M_DIM * E_DIM / 2048), 256, 0, stream>>>(x, Xh);
    cvt_w<<<dim3(16, 16, 4), 256, 0, stream>>>(Wq, Wk, Wv, Wo, Tq, Tk, Tv, To);

    qkv_mfma<<<dim3(M_DIM / 128, E_DIM / 128, 3), 256, 0, stream>>>(
        Xh, Tq, bq, Tk, bk, Tv, bv, Qb, Kb, Vb);

    attn_mfma<<<dim3(40, B_DIM * H_DIM), 256, 0, stream>>>(
        Qb, Kb, Vb, Opart, Mv, Lv, Oh);

    attn_combine<<<dim3(12, B_DIM * H_DIM), 256, 0, stream>>>(Opart, Mv, Lv, Oh);

    out_mfma<<<dim3(M_DIM / 128, E_DIM / 128), 256, 0, stream>>>(
        Oh, To, bo, (float*)d_out);
}